// Round 18
// baseline (249.637 us; speedup 1.0000x reference)
//
#include <hip/hip_runtime.h>
#include <hip/hip_bf16.h>
#include <stdint.h>

#define NN 8192
#define FD 256
#define SLOPE 0.2f
#define LOG2E 1.44269504088896f

typedef float f32x4_t __attribute__((ext_vector_type(4)));
typedef __bf16 bf16x8_t __attribute__((ext_vector_type(8)));
typedef unsigned int u32x2_t __attribute__((ext_vector_type(2)));

__device__ __forceinline__ unsigned short f2bf(float x) {
  unsigned int u = __builtin_bit_cast(unsigned int, x);
  u += 0x7FFFu + ((u >> 16) & 1u);  // RNE
  return (unsigned short)(u >> 16);
}

__device__ __forceinline__ unsigned int cvtpk(float lo, float hi) {
  unsigned int r;
  asm("v_cvt_pk_bf16_f32 %0, %1, %2" : "=v"(r) : "v"(lo), "v"(hi));
  return r;
}

__device__ __forceinline__ void gload_lds16(const void* g, void* l) {
  __builtin_amdgcn_global_load_lds(
      (const __attribute__((address_space(1))) uint32_t*)g,
      (__attribute__((address_space(3))) uint32_t*)l, 16, 0, 0);
}

// ---------------- kernel 0: c1/c2[k] = sum_f W[f][k]*a{1,2}[f] ----------------
__global__ void gat_cvec(const float* __restrict__ W, const float* __restrict__ a,
                         float* __restrict__ c1, float* __restrict__ c2) {
  const int k = threadIdx.x;
  float acc1 = 0.f, acc2 = 0.f;
#pragma unroll 8
  for (int f = 0; f < FD; ++f) {
    float w = W[f * FD + k];
    acc1 = fmaf(w, a[f], acc1);
    acc2 = fmaf(w, a[FD + f], acc2);
  }
  c1[k] = acc1;
  c2[k] = acc2;
}

// ---- fused prep: blocks [0,512) wht | [512,2560) svec ----------------------
// whTK[ktile(64k)][f(256)][k%64] with the G4 XOR swizzle PRE-APPLIED:
// idx = ktile*16384 + f*64 + ((k>>3)^(f&7))*8 + (k&7).   (rule #21)
__launch_bounds__(256)
__global__ void gat_prep(const float* __restrict__ h, const float* __restrict__ W,
                         const float* __restrict__ c1, const float* __restrict__ c2,
                         unsigned short* __restrict__ whTK,
                         float* __restrict__ s1, float* __restrict__ s2) {
  __shared__ __align__(16) float hT[64][64];
  __shared__ __align__(16) float wT[64][64];
  const int b = blockIdx.x;
  const int t = threadIdx.x;

  if (b < 512) {
    const int i0 = (b & 127) * 64;  // k-range (rows of Wh)
    const int f0 = (b >> 7) * 64;
    const int r = t & 63;
    const int kq = t >> 6;
    const int ty = t >> 4;
    const int tx = t & 15;
    float acc[4][4] = {};
    for (int k0 = 0; k0 < FD; k0 += 64) {
#pragma unroll
      for (int kk = 0; kk < 16; kk += 4) {
        float4 v = *(const float4*)(h + (size_t)(i0 + r) * FD + k0 + kq * 16 + kk);
        hT[kq * 16 + kk + 0][r] = v.x;
        hT[kq * 16 + kk + 1][r] = v.y;
        hT[kq * 16 + kk + 2][r] = v.z;
        hT[kq * 16 + kk + 3][r] = v.w;
        float4 u = *(const float4*)(W + (size_t)(f0 + r) * FD + k0 + kq * 16 + kk);
        wT[kq * 16 + kk + 0][r] = u.x;
        wT[kq * 16 + kk + 1][r] = u.y;
        wT[kq * 16 + kk + 2][r] = u.z;
        wT[kq * 16 + kk + 3][r] = u.w;
      }
      __syncthreads();
#pragma unroll 8
      for (int kk = 0; kk < 64; ++kk) {
        float4 av = *(const float4*)&hT[kk][ty * 4];
        float4 bv = *(const float4*)&wT[kk][tx * 4];
        acc[0][0] = fmaf(av.x, bv.x, acc[0][0]);
        acc[0][1] = fmaf(av.x, bv.y, acc[0][1]);
        acc[0][2] = fmaf(av.x, bv.z, acc[0][2]);
        acc[0][3] = fmaf(av.x, bv.w, acc[0][3]);
        acc[1][0] = fmaf(av.y, bv.x, acc[1][0]);
        acc[1][1] = fmaf(av.y, bv.y, acc[1][1]);
        acc[1][2] = fmaf(av.y, bv.z, acc[1][2]);
        acc[1][3] = fmaf(av.y, bv.w, acc[1][3]);
        acc[2][0] = fmaf(av.z, bv.x, acc[2][0]);
        acc[2][1] = fmaf(av.z, bv.y, acc[2][1]);
        acc[2][2] = fmaf(av.z, bv.z, acc[2][2]);
        acc[2][3] = fmaf(av.z, bv.w, acc[2][3]);
        acc[3][0] = fmaf(av.w, bv.x, acc[3][0]);
        acc[3][1] = fmaf(av.w, bv.y, acc[3][1]);
        acc[3][2] = fmaf(av.w, bv.z, acc[3][2]);
        acc[3][3] = fmaf(av.w, bv.w, acc[3][3]);
      }
      __syncthreads();
    }
    const int iv = i0 + ty * 4;
    const int ktile = iv >> 6;
    const int kl = iv & 63;
#pragma unroll
    for (int j = 0; j < 4; ++j) {
      const int f = f0 + tx * 4 + j;
      ushort4 o;
      o.x = f2bf(acc[0][j]);
      o.y = f2bf(acc[1][j]);
      o.z = f2bf(acc[2][j]);
      o.w = f2bf(acc[3][j]);
      const size_t idx = (size_t)ktile * 16384 + (size_t)f * 64 +
                         (size_t)(((kl >> 3) ^ (f & 7)) * 8 + (kl & 7));
      *(ushort4*)(whTK + idx) = o;
    }
  } else {
    const int i = (b - 512) * 4 + (t >> 6);
    const int lane = t & 63;
    float4 hv = *(const float4*)(h + (size_t)i * FD + lane * 4);
    float4 u = *(const float4*)(c1 + lane * 4);
    float4 v = *(const float4*)(c2 + lane * 4);
    float d1 = hv.x * u.x + hv.y * u.y + hv.z * u.z + hv.w * u.w;
    float d2 = hv.x * v.x + hv.y * v.y + hv.z * v.z + hv.w * v.w;
#pragma unroll
    for (int m = 1; m < 64; m <<= 1) {
      d1 += __shfl_xor(d1, m, 64);
      d2 += __shfl_xor(d2, m, 64);
    }
    if (lane == 0) {
      s1[i] = d1 * LOG2E;
      s2[i] = d2 * LOG2E;
    }
  }
}

// ---- attention: raw-adj fused, 2-deep adj prefetch, clobber-free barriers ---
// grid 512 = 64 rs x 8 kq; block 128 rows x 256 f x 1024 k; 16 iters BK=64.
// Per iter: [8 B gload_lds] [P-VALU from CA regs -> swizzled As] [refill CA =
// adj(it+2)] [vmcnt(8)+lgkm(0) barrier: B drained, adj in flight] [64 MFMA]
// [lgkm(0) barrier]. adj issue->use distance = 2 iterations (~3-4k cy).
// waitcnt asms are CLOBBER-FREE, sched_barrier(0)-bracketed (rule #18 / m201
// template) so the waitcnt pass doesn't insert conservative vmcnt(0) drains.
__launch_bounds__(256, 2)
__global__ void gat_attn(const int* __restrict__ adj, const float* __restrict__ s1g,
                         const float* __restrict__ s2g,
                         const unsigned short* __restrict__ whTK,
                         float* __restrict__ accP, float* __restrict__ lP) {
  __shared__ __align__(16) unsigned short Bs[64 * 256];  // [f][k] swz, 32 KB
  __shared__ __align__(16) unsigned short As[128 * 64];  // [row][k] swz, 16 KB
  __shared__ __align__(16) float s2s[1024];              // 4 KB

  const int tid = threadIdx.x;
  const int lane = tid & 63;
  const int w = tid >> 6;
  const int kq = blockIdx.x & 7;
  const int rs = blockIdx.x >> 3;
  const int kbase = kq * 1024;

  // P-phase roles
  const int q = lane >> 4;   // row subgroup 0..3
  const int kx = lane & 15;  // k-chunk (4 ints)
  const int* abase = adj + (size_t)(rs * 128 + w * 32 + q) * NN + kbase + kx * 4;
  float s1v[8];
#pragma unroll
  for (int j = 0; j < 8; ++j) s1v[j] = s1g[rs * 128 + w * 32 + j * 4 + q];

  // MFMA-phase roles
  const int wr = w & 1;
  const int wc = w >> 1;
  const int r16 = lane & 15;
  const int kg = lane >> 4;

  // stage s2 tile (block k-range)
  *(float4*)&s2s[tid * 4] = *(const float4*)(s2g + kbase + tid * 4);

  // prologue: adj(0) -> CA, adj(1) -> NA
  int4 ca[8], na[8];
#pragma unroll
  for (int j = 0; j < 8; ++j) ca[j] = *(const int4*)(abase + (size_t)j * 4 * NN);
#pragma unroll
  for (int j = 0; j < 8; ++j) na[j] = *(const int4*)(abase + (size_t)j * 4 * NN + 64);
  float la[8] = {0.f, 0.f, 0.f, 0.f, 0.f, 0.f, 0.f, 0.f};

  f32x4_t acc[4][8];
  const f32x4_t zero4 = {0.f, 0.f, 0.f, 0.f};
#pragma unroll
  for (int rt = 0; rt < 4; ++rt)
#pragma unroll
    for (int ct = 0; ct < 8; ++ct) acc[rt][ct] = zero4;

  __syncthreads();  // s2s ready (one-time full drain)

#define GAT_IT(IT, CA)                                                                  \
  {                                                                                     \
    /* stage B(IT): 32 KB via 8 gload_lds/wave */                                       \
    const char* bsrc_ = (const char*)whTK + (size_t)(kq * 16 + (IT)) * 32768;           \
    _Pragma("unroll") for (int p = 0; p < 8; ++p)                                       \
        gload_lds16(bsrc_ + w * 8192 + p * 1024 + lane * 16,                            \
                    (char*)Bs + w * 8192 + p * 1024);                                   \
    __builtin_amdgcn_sched_barrier(0);                                                  \
    /* P-phase from CA regs: 8 rows x 4 ks per thread */                                \
    {                                                                                   \
      float4 s2v = *(const float4*)&s2s[(IT) * 64 + kx * 4];                            \
      _Pragma("unroll") for (int j = 0; j < 8; ++j) {                                   \
        const int4 a = CA[j];                                                           \
        float x0 = s1v[j] + s2v.x; x0 = fmaxf(x0, SLOPE * x0);                          \
        float x1 = s1v[j] + s2v.y; x1 = fmaxf(x1, SLOPE * x1);                          \
        float x2 = s1v[j] + s2v.z; x2 = fmaxf(x2, SLOPE * x2);                          \
        float x3 = s1v[j] + s2v.w; x3 = fmaxf(x3, SLOPE * x3);                          \
        float p0 = a.x != 0 ? __builtin_amdgcn_exp2f(x0) : 0.f;                         \
        float p1 = a.y != 0 ? __builtin_amdgcn_exp2f(x1) : 0.f;                         \
        float p2 = a.z != 0 ? __builtin_amdgcn_exp2f(x2) : 0.f;                         \
        float p3 = a.w != 0 ? __builtin_amdgcn_exp2f(x3) : 0.f;                         \
        la[j] += (p0 + p1) + (p2 + p3);                                                 \
        u32x2_t wv;                                                                     \
        wv[0] = cvtpk(p0, p1);                                                          \
        wv[1] = cvtpk(p2, p3);                                                          \
        const int row_ = w * 32 + j * 4 + q;                                            \
        *(u32x2_t*)((char*)As + row_ * 128 + (((kx >> 1) ^ (row_ & 7)) * 16) +          \
                    (kx & 1) * 8) = wv;                                                 \
      }                                                                                 \
    }                                                                                   \
    __builtin_amdgcn_sched_barrier(0);                                                  \
    /* refill CA = adj(IT+2) — in flight across 2 iterations */                         \
    {                                                                                   \
      const int itn_ = ((IT) + 2 < 16) ? (IT) + 2 : (IT);                               \
      _Pragma("unroll") for (int j = 0; j < 8; ++j)                                     \
          CA[j] = *(const int4*)(abase + (size_t)j * 4 * NN + itn_ * 64);               \
    }                                                                                   \
    __builtin_amdgcn_sched_barrier(0);                                                  \
    asm volatile("s_waitcnt vmcnt(8) lgkmcnt(0)");                                      \
    __builtin_amdgcn_s_barrier();                                                       \
    __builtin_amdgcn_sched_barrier(0);                                                  \
    /* MFMA phase: 64 MFMA/wave */                                                      \
    _Pragma("unroll") for (int kc = 0; kc < 2; ++kc) {                                  \
      const int ch = kc * 4 + kg;                                                       \
      bf16x8_t a0, a1, a2, a3;                                                          \
      {                                                                                 \
        const int row0 = wr * 64 + r16;                                                 \
        a0 = *(const bf16x8_t*)((const char*)As + (row0 + 0) * 128 + ((ch ^ ((row0 + 0) & 7)) * 16));   \
        a1 = *(const bf16x8_t*)((const char*)As + (row0 + 16) * 128 + ((ch ^ ((row0 + 16) & 7)) * 16)); \
        a2 = *(const bf16x8_t*)((const char*)As + (row0 + 32) * 128 + ((ch ^ ((row0 + 32) & 7)) * 16)); \
        a3 = *(const bf16x8_t*)((const char*)As + (row0 + 48) * 128 + ((ch ^ ((row0 + 48) & 7)) * 16)); \
      }                                                                                 \
      _Pragma("unroll") for (int cp = 0; cp < 2; ++cp) {                                \
        bf16x8_t b0, b1, b2, b3;                                                        \
        {                                                                               \
          const int f0l = wc * 128 + cp * 64 + r16;                                     \
          b0 = *(const bf16x8_t*)((const char*)Bs + (f0l + 0) * 128 + ((ch ^ ((f0l + 0) & 7)) * 16));   \
          b1 = *(const bf16x8_t*)((const char*)Bs + (f0l + 16) * 128 + ((ch ^ ((f0l + 16) & 7)) * 16)); \
          b2 = *(const bf16x8_t*)((const char*)Bs + (f0l + 32) * 128 + ((ch ^ ((f0l + 32) & 7)) * 16)); \
          b3 = *(const bf16x8_t*)((const char*)Bs + (f0l + 48) * 128 + ((ch ^ ((f0l + 48) & 7)) * 16)); \
        }                                                                               \
        const int c0 = cp * 4;                                                          \
        acc[0][c0 + 0] = __builtin_amdgcn_mfma_f32_16x16x32_bf16(a0, b0, acc[0][c0 + 0], 0, 0, 0); \
        acc[0][c0 + 1] = __builtin_amdgcn_mfma_f32_16x16x32_bf16(a0, b1, acc[0][c0 + 1], 0, 0, 0); \
        acc[0][c0 + 2] = __builtin_amdgcn_mfma_f32_16x16x32_bf16(a0, b2, acc[0][c0 + 2], 0, 0, 0); \
        acc[0][c0 + 3] = __builtin_amdgcn_mfma_f32_16x16x32_bf16(a0, b3, acc[0][c0 + 3], 0, 0, 0); \
        acc[1][c0 + 0] = __builtin_amdgcn_mfma_f32_16x16x32_bf16(a1, b0, acc[1][c0 + 0], 0, 0, 0); \
        acc[1][c0 + 1] = __builtin_amdgcn_mfma_f32_16x16x32_bf16(a1, b1, acc[1][c0 + 1], 0, 0, 0); \
        acc[1][c0 + 2] = __builtin_amdgcn_mfma_f32_16x16x32_bf16(a1, b2, acc[1][c0 + 2], 0, 0, 0); \
        acc[1][c0 + 3] = __builtin_amdgcn_mfma_f32_16x16x32_bf16(a1, b3, acc[1][c0 + 3], 0, 0, 0); \
        acc[2][c0 + 0] = __builtin_amdgcn_mfma_f32_16x16x32_bf16(a2, b0, acc[2][c0 + 0], 0, 0, 0); \
        acc[2][c0 + 1] = __builtin_amdgcn_mfma_f32_16x16x32_bf16(a2, b1, acc[2][c0 + 1], 0, 0, 0); \
        acc[2][c0 + 2] = __builtin_amdgcn_mfma_f32_16x16x32_bf16(a2, b2, acc[2][c0 + 2], 0, 0, 0); \
        acc[2][c0 + 3] = __builtin_amdgcn_mfma_f32_16x16x32_bf16(a2, b3, acc[2][c0 + 3], 0, 0, 0); \
        acc[3][c0 + 0] = __builtin_amdgcn_mfma_f32_16x16x32_bf16(a3, b0, acc[3][c0 + 0], 0, 0, 0); \
        acc[3][c0 + 1] = __builtin_amdgcn_mfma_f32_16x16x32_bf16(a3, b1, acc[3][c0 + 1], 0, 0, 0); \
        acc[3][c0 + 2] = __builtin_amdgcn_mfma_f32_16x16x32_bf16(a3, b2, acc[3][c0 + 2], 0, 0, 0); \
        acc[3][c0 + 3] = __builtin_amdgcn_mfma_f32_16x16x32_bf16(a3, b3, acc[3][c0 + 3], 0, 0, 0); \
      }                                                                                 \
    }                                                                                   \
    __builtin_amdgcn_sched_barrier(0);                                                  \
    asm volatile("s_waitcnt lgkmcnt(0)");                                               \
    __builtin_amdgcn_s_barrier();                                                       \
    __builtin_amdgcn_sched_barrier(0);                                                  \
  }

  for (int itp = 0; itp < 8; ++itp) {
    GAT_IT(itp * 2, ca)
    GAT_IT(itp * 2 + 1, na)
  }
#undef GAT_IT

  // ---- l: reduce each row over its 16 k-chunk lanes, write directly ----
#pragma unroll
  for (int j = 0; j < 8; ++j) {
    float v = la[j];
    v += __shfl_xor(v, 1, 64);
    v += __shfl_xor(v, 2, 64);
    v += __shfl_xor(v, 4, 64);
    v += __shfl_xor(v, 8, 64);
    if ((lane & 15) == 0)
      lP[(size_t)kq * NN + rs * 128 + w * 32 + j * 4 + q] = v;
  }

  // ---- acc partials ----
  float* ap = accP + (size_t)kq * NN * FD;
#pragma unroll
  for (int rt = 0; rt < 4; ++rt) {
#pragma unroll
    for (int ct = 0; ct < 8; ++ct) {
      const int col = wc * 128 + ct * 16 + r16;
#pragma unroll
      for (int g = 0; g < 4; ++g) {
        const int row = rs * 128 + wr * 64 + rt * 16 + kg * 4 + g;
        ap[(size_t)row * FD + col] = acc[rt][ct][g];
      }
    }
  }
}

// ---------------- merge: out[i][f] = sum_kq accP / sum_kq lP -----------------
__global__ void gat_merge(const float* __restrict__ accP, const float* __restrict__ lP,
                          float* __restrict__ out) {
  const int i = blockIdx.x;
  const int f = threadIdx.x;
  float s = 0.f, l = 0.f;
#pragma unroll
  for (int q = 0; q < 8; ++q) {
    s += accP[((size_t)q * NN + i) * FD + f];
    l += lP[(size_t)q * NN + i];
  }
  out[(size_t)i * FD + f] = s / l;
}

extern "C" void kernel_launch(void* const* d_in, const int* in_sizes, int n_in,
                              void* d_out, int out_size, void* d_ws, size_t ws_size,
                              hipStream_t stream) {
  const float* h = (const float*)d_in[0];
  const int* adj = (const int*)d_in[1];
  const float* W = (const float*)d_in[2];
  const float* a = (const float*)d_in[3];
  float* out = (float*)d_out;

  char* ws = (char*)d_ws;
  unsigned short* whTK = (unsigned short*)ws;                // 4 MB
  float* s1 = (float*)(ws + 4194304);                        // 32 KB
  float* s2 = (float*)(ws + 4194304 + 32768);                // 32 KB
  float* c1 = (float*)(ws + 4194304 + 65536);                // 1 KB
  float* c2 = (float*)(ws + 4194304 + 65536 + 1024);         // 1 KB
  float* accP = (float*)(ws + 16777216);                     // 8 x 8 MB
  float* lP = (float*)(ws + 16777216 + 8ull * NN * FD * 4);  // 256 KB

  gat_cvec<<<1, 256, 0, stream>>>(W, a, c1, c2);
  gat_prep<<<2560, 256, 0, stream>>>(h, W, c1, c2, whTK, s1, s2);
  gat_attn<<<512, 256, 0, stream>>>(adj, s1, s2, whTK, accP, lP);
  gat_merge<<<NN, FD, 0, stream>>>(accP, lP, out);
}

// Round 19
// 137.006 us; speedup vs baseline: 1.8221x; 1.8221x over previous
//
#include <hip/hip_runtime.h>
#include <hip/hip_bf16.h>
#include <stdint.h>

#define NN 8192
#define FD 256
#define SLOPE 0.2f
#define LOG2E 1.44269504088896f

typedef float f32x4_t __attribute__((ext_vector_type(4)));
typedef __bf16 bf16x8_t __attribute__((ext_vector_type(8)));
typedef unsigned int u32x2_t __attribute__((ext_vector_type(2)));

__device__ __forceinline__ unsigned short f2bf(float x) {
  unsigned int u = __builtin_bit_cast(unsigned int, x);
  u += 0x7FFFu + ((u >> 16) & 1u);  // RNE
  return (unsigned short)(u >> 16);
}

__device__ __forceinline__ unsigned int cvtpk(float lo, float hi) {
  unsigned int r;
  asm("v_cvt_pk_bf16_f32 %0, %1, %2" : "=v"(r) : "v"(lo), "v"(hi));
  return r;
}

__device__ __forceinline__ void gload_lds16(const void* g, void* l) {
  __builtin_amdgcn_global_load_lds(
      (const __attribute__((address_space(1))) uint32_t*)g,
      (__attribute__((address_space(3))) uint32_t*)l, 16, 0, 0);
}

// ---------------- kernel 0: c1/c2[k] = sum_f W[f][k]*a{1,2}[f] ----------------
__global__ void gat_cvec(const float* __restrict__ W, const float* __restrict__ a,
                         float* __restrict__ c1, float* __restrict__ c2) {
  const int k = threadIdx.x;
  float acc1 = 0.f, acc2 = 0.f;
#pragma unroll 8
  for (int f = 0; f < FD; ++f) {
    float w = W[f * FD + k];
    acc1 = fmaf(w, a[f], acc1);
    acc2 = fmaf(w, a[FD + f], acc2);
  }
  c1[k] = acc1;
  c2[k] = acc2;
}

// ---- fused prep: blocks [0,512) wht | [512,2560) svec ----------------------
// whTK[ktile(64k)][f(256)][k%64] with the G4 XOR swizzle PRE-APPLIED:
// idx = ktile*16384 + f*64 + ((k>>3)^(f&7))*8 + (k&7).   (rule #21)
__launch_bounds__(256)
__global__ void gat_prep(const float* __restrict__ h, const float* __restrict__ W,
                         const float* __restrict__ c1, const float* __restrict__ c2,
                         unsigned short* __restrict__ whTK,
                         float* __restrict__ s1, float* __restrict__ s2) {
  __shared__ __align__(16) float hT[64][64];
  __shared__ __align__(16) float wT[64][64];
  const int b = blockIdx.x;
  const int t = threadIdx.x;

  if (b < 512) {
    const int i0 = (b & 127) * 64;  // k-range (rows of Wh)
    const int f0 = (b >> 7) * 64;
    const int r = t & 63;
    const int kq = t >> 6;
    const int ty = t >> 4;
    const int tx = t & 15;
    float acc[4][4] = {};
    for (int k0 = 0; k0 < FD; k0 += 64) {
#pragma unroll
      for (int kk = 0; kk < 16; kk += 4) {
        float4 v = *(const float4*)(h + (size_t)(i0 + r) * FD + k0 + kq * 16 + kk);
        hT[kq * 16 + kk + 0][r] = v.x;
        hT[kq * 16 + kk + 1][r] = v.y;
        hT[kq * 16 + kk + 2][r] = v.z;
        hT[kq * 16 + kk + 3][r] = v.w;
        float4 u = *(const float4*)(W + (size_t)(f0 + r) * FD + k0 + kq * 16 + kk);
        wT[kq * 16 + kk + 0][r] = u.x;
        wT[kq * 16 + kk + 1][r] = u.y;
        wT[kq * 16 + kk + 2][r] = u.z;
        wT[kq * 16 + kk + 3][r] = u.w;
      }
      __syncthreads();
#pragma unroll 8
      for (int kk = 0; kk < 64; ++kk) {
        float4 av = *(const float4*)&hT[kk][ty * 4];
        float4 bv = *(const float4*)&wT[kk][tx * 4];
        acc[0][0] = fmaf(av.x, bv.x, acc[0][0]);
        acc[0][1] = fmaf(av.x, bv.y, acc[0][1]);
        acc[0][2] = fmaf(av.x, bv.z, acc[0][2]);
        acc[0][3] = fmaf(av.x, bv.w, acc[0][3]);
        acc[1][0] = fmaf(av.y, bv.x, acc[1][0]);
        acc[1][1] = fmaf(av.y, bv.y, acc[1][1]);
        acc[1][2] = fmaf(av.y, bv.z, acc[1][2]);
        acc[1][3] = fmaf(av.y, bv.w, acc[1][3]);
        acc[2][0] = fmaf(av.z, bv.x, acc[2][0]);
        acc[2][1] = fmaf(av.z, bv.y, acc[2][1]);
        acc[2][2] = fmaf(av.z, bv.z, acc[2][2]);
        acc[2][3] = fmaf(av.z, bv.w, acc[2][3]);
        acc[3][0] = fmaf(av.w, bv.x, acc[3][0]);
        acc[3][1] = fmaf(av.w, bv.y, acc[3][1]);
        acc[3][2] = fmaf(av.w, bv.z, acc[3][2]);
        acc[3][3] = fmaf(av.w, bv.w, acc[3][3]);
      }
      __syncthreads();
    }
    const int iv = i0 + ty * 4;
    const int ktile = iv >> 6;
    const int kl = iv & 63;
#pragma unroll
    for (int j = 0; j < 4; ++j) {
      const int f = f0 + tx * 4 + j;
      ushort4 o;
      o.x = f2bf(acc[0][j]);
      o.y = f2bf(acc[1][j]);
      o.z = f2bf(acc[2][j]);
      o.w = f2bf(acc[3][j]);
      const size_t idx = (size_t)ktile * 16384 + (size_t)f * 64 +
                         (size_t)(((kl >> 3) ^ (f & 7)) * 8 + (kl & 7));
      *(ushort4*)(whTK + idx) = o;
    }
  } else {
    const int i = (b - 512) * 4 + (t >> 6);
    const int lane = t & 63;
    float4 hv = *(const float4*)(h + (size_t)i * FD + lane * 4);
    float4 u = *(const float4*)(c1 + lane * 4);
    float4 v = *(const float4*)(c2 + lane * 4);
    float d1 = hv.x * u.x + hv.y * u.y + hv.z * u.z + hv.w * u.w;
    float d2 = hv.x * v.x + hv.y * v.y + hv.z * v.z + hv.w * v.w;
#pragma unroll
    for (int m = 1; m < 64; m <<= 1) {
      d1 += __shfl_xor(d1, m, 64);
      d2 += __shfl_xor(d2, m, 64);
    }
    if (lane == 0) {
      s1[i] = d1 * LOG2E;
      s2[i] = d2 * LOG2E;
    }
  }
}

// ---- attention: raw-adj fused (r17 structure), clobber-free barriers --------
// grid 512 = 64 rs x 8 kq; block 128 rows x 256 f x 1024 k; 16 iters BK=64.
// Per iter: [8 B gload_lds] [P-VALU from adj regs -> swizzled As] [reload
// adj(it+1)] [vmcnt(8)+lgkm(0) barrier, CLOBBER-FREE: B drained, adj loads
// stay in flight (T4)] [64 MFMA/wave] [lgkm(0) barrier, clobber-free].
// 1-deep adj prefetch only (r18's 2-deep spilled: VGPR cap has no headroom).
__launch_bounds__(256, 2)
__global__ void gat_attn(const int* __restrict__ adj, const float* __restrict__ s1g,
                         const float* __restrict__ s2g,
                         const unsigned short* __restrict__ whTK,
                         float* __restrict__ accP, float* __restrict__ lP) {
  __shared__ __align__(16) unsigned short Bs[64 * 256];  // [f][k] swz, 32 KB
  __shared__ __align__(16) unsigned short As[128 * 64];  // [row][k] swz, 16 KB
  __shared__ __align__(16) float s2s[1024];              // 4 KB

  const int tid = threadIdx.x;
  const int lane = tid & 63;
  const int w = tid >> 6;
  const int kq = blockIdx.x & 7;
  const int rs = blockIdx.x >> 3;
  const int kbase = kq * 1024;

  // P-phase roles
  const int q = lane >> 4;   // row subgroup 0..3
  const int kx = lane & 15;  // k-chunk (4 ints)
  const int* abase = adj + (size_t)(rs * 128 + w * 32 + q) * NN + kbase + kx * 4;
  float s1v[8];
#pragma unroll
  for (int j = 0; j < 8; ++j) s1v[j] = s1g[rs * 128 + w * 32 + j * 4 + q];

  // MFMA-phase roles
  const int wr = w & 1;
  const int wc = w >> 1;
  const int r16 = lane & 15;
  const int kg = lane >> 4;

  // stage s2 tile (block k-range)
  *(float4*)&s2s[tid * 4] = *(const float4*)(s2g + kbase + tid * 4);

  // prologue: adj(0) into regs
  int4 ca[8];
#pragma unroll
  for (int j = 0; j < 8; ++j) ca[j] = *(const int4*)(abase + (size_t)j * 4 * NN);
  float la[8] = {0.f, 0.f, 0.f, 0.f, 0.f, 0.f, 0.f, 0.f};

  f32x4_t acc[4][8];
  const f32x4_t zero4 = {0.f, 0.f, 0.f, 0.f};
#pragma unroll
  for (int rt = 0; rt < 4; ++rt)
#pragma unroll
    for (int ct = 0; ct < 8; ++ct) acc[rt][ct] = zero4;

  __syncthreads();  // s2s ready (drains prologue vmem too — one-time)

  for (int it = 0; it < 16; ++it) {
    // ---- stage B(it): 32 KB via 8 gload_lds/wave ----
    {
      const char* bsrc = (const char*)whTK + (size_t)(kq * 16 + it) * 32768;
      char* bdst = (char*)Bs;
#pragma unroll
      for (int p = 0; p < 8; ++p)
        gload_lds16(bsrc + w * 8192 + p * 1024 + lane * 16, bdst + w * 8192 + p * 1024);
    }
    __builtin_amdgcn_sched_barrier(0);

    // ---- P-phase from adj regs: 8 rows x 4 ks per thread ----
    {
      float4 s2v = *(const float4*)&s2s[it * 64 + kx * 4];
#pragma unroll
      for (int j = 0; j < 8; ++j) {
        const int4 a = ca[j];
        float x0 = s1v[j] + s2v.x; x0 = fmaxf(x0, SLOPE * x0);
        float x1 = s1v[j] + s2v.y; x1 = fmaxf(x1, SLOPE * x1);
        float x2 = s1v[j] + s2v.z; x2 = fmaxf(x2, SLOPE * x2);
        float x3 = s1v[j] + s2v.w; x3 = fmaxf(x3, SLOPE * x3);
        float p0 = a.x != 0 ? __builtin_amdgcn_exp2f(x0) : 0.f;
        float p1 = a.y != 0 ? __builtin_amdgcn_exp2f(x1) : 0.f;
        float p2 = a.z != 0 ? __builtin_amdgcn_exp2f(x2) : 0.f;
        float p3 = a.w != 0 ? __builtin_amdgcn_exp2f(x3) : 0.f;
        la[j] += (p0 + p1) + (p2 + p3);
        u32x2_t wv;
        wv[0] = cvtpk(p0, p1);
        wv[1] = cvtpk(p2, p3);
        const int row = w * 32 + j * 4 + q;
        *(u32x2_t*)((char*)As + row * 128 + (((kx >> 1) ^ (row & 7)) * 16) + (kx & 1) * 8) = wv;
      }
    }

    // ---- reload adj(it+1) (stays in flight across both barriers) ----
    {
      const int itn = (it + 1 < 16) ? it + 1 : it;
#pragma unroll
      for (int j = 0; j < 8; ++j)
        ca[j] = *(const int4*)(abase + (size_t)j * 4 * NN + itn * 64);
    }
    __builtin_amdgcn_sched_barrier(0);

    // ---- barrier-1: B staged (vmcnt(8): adj loads in flight), A visible ----
    asm volatile("s_waitcnt vmcnt(8) lgkmcnt(0)");
    __builtin_amdgcn_s_barrier();
    __builtin_amdgcn_sched_barrier(0);

    // ---- MFMA phase: 64 MFMA/wave ----
    {
#pragma unroll
      for (int kc = 0; kc < 2; ++kc) {
        const int ch = kc * 4 + kg;
        bf16x8_t a0, a1, a2, a3;
        {
          const int row0 = wr * 64 + r16;
          a0 = *(const bf16x8_t*)((const char*)As + (row0 + 0) * 128 + ((ch ^ ((row0 + 0) & 7)) * 16));
          a1 = *(const bf16x8_t*)((const char*)As + (row0 + 16) * 128 + ((ch ^ ((row0 + 16) & 7)) * 16));
          a2 = *(const bf16x8_t*)((const char*)As + (row0 + 32) * 128 + ((ch ^ ((row0 + 32) & 7)) * 16));
          a3 = *(const bf16x8_t*)((const char*)As + (row0 + 48) * 128 + ((ch ^ ((row0 + 48) & 7)) * 16));
        }
#pragma unroll
        for (int cp = 0; cp < 2; ++cp) {
          bf16x8_t b0, b1, b2, b3;
          {
            const int f0l = wc * 128 + cp * 64 + r16;
            b0 = *(const bf16x8_t*)((const char*)Bs + (f0l + 0) * 128 + ((ch ^ ((f0l + 0) & 7)) * 16));
            b1 = *(const bf16x8_t*)((const char*)Bs + (f0l + 16) * 128 + ((ch ^ ((f0l + 16) & 7)) * 16));
            b2 = *(const bf16x8_t*)((const char*)Bs + (f0l + 32) * 128 + ((ch ^ ((f0l + 32) & 7)) * 16));
            b3 = *(const bf16x8_t*)((const char*)Bs + (f0l + 48) * 128 + ((ch ^ ((f0l + 48) & 7)) * 16));
          }
          const int c0 = cp * 4;
          acc[0][c0 + 0] = __builtin_amdgcn_mfma_f32_16x16x32_bf16(a0, b0, acc[0][c0 + 0], 0, 0, 0);
          acc[0][c0 + 1] = __builtin_amdgcn_mfma_f32_16x16x32_bf16(a0, b1, acc[0][c0 + 1], 0, 0, 0);
          acc[0][c0 + 2] = __builtin_amdgcn_mfma_f32_16x16x32_bf16(a0, b2, acc[0][c0 + 2], 0, 0, 0);
          acc[0][c0 + 3] = __builtin_amdgcn_mfma_f32_16x16x32_bf16(a0, b3, acc[0][c0 + 3], 0, 0, 0);
          acc[1][c0 + 0] = __builtin_amdgcn_mfma_f32_16x16x32_bf16(a1, b0, acc[1][c0 + 0], 0, 0, 0);
          acc[1][c0 + 1] = __builtin_amdgcn_mfma_f32_16x16x32_bf16(a1, b1, acc[1][c0 + 1], 0, 0, 0);
          acc[1][c0 + 2] = __builtin_amdgcn_mfma_f32_16x16x32_bf16(a1, b2, acc[1][c0 + 2], 0, 0, 0);
          acc[1][c0 + 3] = __builtin_amdgcn_mfma_f32_16x16x32_bf16(a1, b3, acc[1][c0 + 3], 0, 0, 0);
          acc[2][c0 + 0] = __builtin_amdgcn_mfma_f32_16x16x32_bf16(a2, b0, acc[2][c0 + 0], 0, 0, 0);
          acc[2][c0 + 1] = __builtin_amdgcn_mfma_f32_16x16x32_bf16(a2, b1, acc[2][c0 + 1], 0, 0, 0);
          acc[2][c0 + 2] = __builtin_amdgcn_mfma_f32_16x16x32_bf16(a2, b2, acc[2][c0 + 2], 0, 0, 0);
          acc[2][c0 + 3] = __builtin_amdgcn_mfma_f32_16x16x32_bf16(a2, b3, acc[2][c0 + 3], 0, 0, 0);
          acc[3][c0 + 0] = __builtin_amdgcn_mfma_f32_16x16x32_bf16(a3, b0, acc[3][c0 + 0], 0, 0, 0);
          acc[3][c0 + 1] = __builtin_amdgcn_mfma_f32_16x16x32_bf16(a3, b1, acc[3][c0 + 1], 0, 0, 0);
          acc[3][c0 + 2] = __builtin_amdgcn_mfma_f32_16x16x32_bf16(a3, b2, acc[3][c0 + 2], 0, 0, 0);
          acc[3][c0 + 3] = __builtin_amdgcn_mfma_f32_16x16x32_bf16(a3, b3, acc[3][c0 + 3], 0, 0, 0);
        }
      }
    }
    __builtin_amdgcn_sched_barrier(0);

    // ---- barrier-2: LDS reads retired; adj loads stay in flight ----
    asm volatile("s_waitcnt lgkmcnt(0)");
    __builtin_amdgcn_s_barrier();
    __builtin_amdgcn_sched_barrier(0);
  }

  // ---- l: reduce each row over its 16 k-chunk lanes, write directly ----
#pragma unroll
  for (int j = 0; j < 8; ++j) {
    float v = la[j];
    v += __shfl_xor(v, 1, 64);
    v += __shfl_xor(v, 2, 64);
    v += __shfl_xor(v, 4, 64);
    v += __shfl_xor(v, 8, 64);
    if ((lane & 15) == 0)
      lP[(size_t)kq * NN + rs * 128 + w * 32 + j * 4 + q] = v;
  }

  // ---- acc partials ----
  float* ap = accP + (size_t)kq * NN * FD;
#pragma unroll
  for (int rt = 0; rt < 4; ++rt) {
#pragma unroll
    for (int ct = 0; ct < 8; ++ct) {
      const int col = wc * 128 + ct * 16 + r16;
#pragma unroll
      for (int g = 0; g < 4; ++g) {
        const int row = rs * 128 + wr * 64 + rt * 16 + kg * 4 + g;
        ap[(size_t)row * FD + col] = acc[rt][ct][g];
      }
    }
  }
}

// ---------------- merge: out[i][f] = sum_kq accP / sum_kq lP -----------------
__global__ void gat_merge(const float* __restrict__ accP, const float* __restrict__ lP,
                          float* __restrict__ out) {
  const int i = blockIdx.x;
  const int f = threadIdx.x;
  float s = 0.f, l = 0.f;
#pragma unroll
  for (int q = 0; q < 8; ++q) {
    s += accP[((size_t)q * NN + i) * FD + f];
    l += lP[(size_t)q * NN + i];
  }
  out[(size_t)i * FD + f] = s / l;
}

extern "C" void kernel_launch(void* const* d_in, const int* in_sizes, int n_in,
                              void* d_out, int out_size, void* d_ws, size_t ws_size,
                              hipStream_t stream) {
  const float* h = (const float*)d_in[0];
  const int* adj = (const int*)d_in[1];
  const float* W = (const float*)d_in[2];
  const float* a = (const float*)d_in[3];
  float* out = (float*)d_out;

  char* ws = (char*)d_ws;
  unsigned short* whTK = (unsigned short*)ws;                // 4 MB
  float* s1 = (float*)(ws + 4194304);                        // 32 KB
  float* s2 = (float*)(ws + 4194304 + 32768);                // 32 KB
  float* c1 = (float*)(ws + 4194304 + 65536);                // 1 KB
  float* c2 = (float*)(ws + 4194304 + 65536 + 1024);         // 1 KB
  float* accP = (float*)(ws + 16777216);                     // 8 x 8 MB
  float* lP = (float*)(ws + 16777216 + 8ull * NN * FD * 4);  // 256 KB

  gat_cvec<<<1, 256, 0, stream>>>(W, a, c1, c2);
  gat_prep<<<2560, 256, 0, stream>>>(h, W, c1, c2, whTK, s1, s2);
  gat_attn<<<512, 256, 0, stream>>>(adj, s1, s2, whTK, accP, lP);
  gat_merge<<<NN, FD, 0, stream>>>(accP, lP, out);
}

// Round 21
// 135.053 us; speedup vs baseline: 1.8484x; 1.0145x over previous
//
#include <hip/hip_runtime.h>
#include <hip/hip_bf16.h>
#include <stdint.h>

#define NN 8192
#define FD 256
#define SLOPE 0.2f
#define LOG2E 1.44269504088896f

typedef float f32x4_t __attribute__((ext_vector_type(4)));
typedef __bf16 bf16x8_t __attribute__((ext_vector_type(8)));
typedef unsigned int u32x2_t __attribute__((ext_vector_type(2)));

__device__ __forceinline__ unsigned short f2bf(float x) {
  unsigned int u = __builtin_bit_cast(unsigned int, x);
  u += 0x7FFFu + ((u >> 16) & 1u);  // RNE
  return (unsigned short)(u >> 16);
}

__device__ __forceinline__ unsigned int cvtpk(float lo, float hi) {
  unsigned int r;
  asm("v_cvt_pk_bf16_f32 %0, %1, %2" : "=v"(r) : "v"(lo), "v"(hi));
  return r;
}

__device__ __forceinline__ void gload_lds16(const void* g, void* l) {
  __builtin_amdgcn_global_load_lds(
      (const __attribute__((address_space(1))) uint32_t*)g,
      (__attribute__((address_space(3))) uint32_t*)l, 16, 0, 0);
}

// ---------------- kernel 0: c1/c2[k] = sum_f W[f][k]*a{1,2}[f] ----------------
__global__ void gat_cvec(const float* __restrict__ W, const float* __restrict__ a,
                         float* __restrict__ c1, float* __restrict__ c2) {
  const int k = threadIdx.x;
  float acc1 = 0.f, acc2 = 0.f;
#pragma unroll 8
  for (int f = 0; f < FD; ++f) {
    float w = W[f * FD + k];
    acc1 = fmaf(w, a[f], acc1);
    acc2 = fmaf(w, a[FD + f], acc2);
  }
  c1[k] = acc1;
  c2[k] = acc2;
}

// ---- fused prep: blocks [0,512) wht | [512,2560) svec ----------------------
// whTK[ktile(64k)][f(256)][k%64] with the G4 XOR swizzle PRE-APPLIED:
// idx = ktile*16384 + f*64 + ((k>>3)^(f&7))*8 + (k&7).   (rule #21)
__launch_bounds__(256)
__global__ void gat_prep(const float* __restrict__ h, const float* __restrict__ W,
                         const float* __restrict__ c1, const float* __restrict__ c2,
                         unsigned short* __restrict__ whTK,
                         float* __restrict__ s1, float* __restrict__ s2) {
  __shared__ __align__(16) float hT[64][64];
  __shared__ __align__(16) float wT[64][64];
  const int b = blockIdx.x;
  const int t = threadIdx.x;

  if (b < 512) {
    const int i0 = (b & 127) * 64;  // k-range (rows of Wh)
    const int f0 = (b >> 7) * 64;
    const int r = t & 63;
    const int kq = t >> 6;
    const int ty = t >> 4;
    const int tx = t & 15;
    float acc[4][4] = {};
    for (int k0 = 0; k0 < FD; k0 += 64) {
#pragma unroll
      for (int kk = 0; kk < 16; kk += 4) {
        float4 v = *(const float4*)(h + (size_t)(i0 + r) * FD + k0 + kq * 16 + kk);
        hT[kq * 16 + kk + 0][r] = v.x;
        hT[kq * 16 + kk + 1][r] = v.y;
        hT[kq * 16 + kk + 2][r] = v.z;
        hT[kq * 16 + kk + 3][r] = v.w;
        float4 u = *(const float4*)(W + (size_t)(f0 + r) * FD + k0 + kq * 16 + kk);
        wT[kq * 16 + kk + 0][r] = u.x;
        wT[kq * 16 + kk + 1][r] = u.y;
        wT[kq * 16 + kk + 2][r] = u.z;
        wT[kq * 16 + kk + 3][r] = u.w;
      }
      __syncthreads();
#pragma unroll 8
      for (int kk = 0; kk < 64; ++kk) {
        float4 av = *(const float4*)&hT[kk][ty * 4];
        float4 bv = *(const float4*)&wT[kk][tx * 4];
        acc[0][0] = fmaf(av.x, bv.x, acc[0][0]);
        acc[0][1] = fmaf(av.x, bv.y, acc[0][1]);
        acc[0][2] = fmaf(av.x, bv.z, acc[0][2]);
        acc[0][3] = fmaf(av.x, bv.w, acc[0][3]);
        acc[1][0] = fmaf(av.y, bv.x, acc[1][0]);
        acc[1][1] = fmaf(av.y, bv.y, acc[1][1]);
        acc[1][2] = fmaf(av.y, bv.z, acc[1][2]);
        acc[1][3] = fmaf(av.y, bv.w, acc[1][3]);
        acc[2][0] = fmaf(av.z, bv.x, acc[2][0]);
        acc[2][1] = fmaf(av.z, bv.y, acc[2][1]);
        acc[2][2] = fmaf(av.z, bv.z, acc[2][2]);
        acc[2][3] = fmaf(av.z, bv.w, acc[2][3]);
        acc[3][0] = fmaf(av.w, bv.x, acc[3][0]);
        acc[3][1] = fmaf(av.w, bv.y, acc[3][1]);
        acc[3][2] = fmaf(av.w, bv.z, acc[3][2]);
        acc[3][3] = fmaf(av.w, bv.w, acc[3][3]);
      }
      __syncthreads();
    }
    const int iv = i0 + ty * 4;
    const int ktile = iv >> 6;
    const int kl = iv & 63;
#pragma unroll
    for (int j = 0; j < 4; ++j) {
      const int f = f0 + tx * 4 + j;
      ushort4 o;
      o.x = f2bf(acc[0][j]);
      o.y = f2bf(acc[1][j]);
      o.z = f2bf(acc[2][j]);
      o.w = f2bf(acc[3][j]);
      const size_t idx = (size_t)ktile * 16384 + (size_t)f * 64 +
                         (size_t)(((kl >> 3) ^ (f & 7)) * 8 + (kl & 7));
      *(ushort4*)(whTK + idx) = o;
    }
  } else {
    const int i = (b - 512) * 4 + (t >> 6);
    const int lane = t & 63;
    float4 hv = *(const float4*)(h + (size_t)i * FD + lane * 4);
    float4 u = *(const float4*)(c1 + lane * 4);
    float4 v = *(const float4*)(c2 + lane * 4);
    float d1 = hv.x * u.x + hv.y * u.y + hv.z * u.z + hv.w * u.w;
    float d2 = hv.x * v.x + hv.y * v.y + hv.z * v.z + hv.w * v.w;
#pragma unroll
    for (int m = 1; m < 64; m <<= 1) {
      d1 += __shfl_xor(d1, m, 64);
      d2 += __shfl_xor(d2, m, 64);
    }
    if (lane == 0) {
      s1[i] = d1 * LOG2E;
      s2[i] = d2 * LOG2E;
    }
  }
}

// ---- attention: raw-adj fused. 128 rows x 256 f per block, m97-style -------
// grid 512 = 64 rs x 8 kq; block (rs,kq) reads adj[rs*128..)[kq*1024..) --
// each adj element read EXACTLY ONCE device-wide (268 MB stream absorbed into
// the GEMM pipeline). Per iter: [stage B 32KB gload_lds] [P-VALU from adj regs
// -> swizzled As] [reload adj(it+1) -> regs] [vmcnt(8)+lgkm(0) raw barrier: B
// drained, adj left in flight (T4)] [64 MFMA/wave] [lgkm(0) raw barrier].
// P mapping: wave w rows w*32..+31; lane q=lane>>4 row-sub, kx=lane&15.
__launch_bounds__(256, 2)
__global__ void gat_attn(const int* __restrict__ adj, const float* __restrict__ s1g,
                         const float* __restrict__ s2g,
                         const unsigned short* __restrict__ whTK,
                         float* __restrict__ accP, float* __restrict__ lP) {
  __shared__ __align__(16) unsigned short Bs[64 * 256];  // [f][k] swz, 32 KB
  __shared__ __align__(16) unsigned short As[128 * 64];  // [row][k] swz, 16 KB
  __shared__ __align__(16) float s2s[1024];              // 4 KB

  const int tid = threadIdx.x;
  const int lane = tid & 63;
  const int w = tid >> 6;
  const int kq = blockIdx.x & 7;
  const int rs = blockIdx.x >> 3;
  const int kbase = kq * 1024;

  // P-phase roles
  const int q = lane >> 4;   // row subgroup 0..3
  const int kx = lane & 15;  // k-chunk (4 ints)
  const int* abase = adj + (size_t)(rs * 128 + w * 32 + q) * NN + kbase + kx * 4;
  float s1v[8];
#pragma unroll
  for (int j = 0; j < 8; ++j) s1v[j] = s1g[rs * 128 + w * 32 + j * 4 + q];

  // MFMA-phase roles
  const int wr = w & 1;
  const int wc = w >> 1;
  const int r16 = lane & 15;
  const int kg = lane >> 4;

  // stage s2 tile (block k-range)
  *(float4*)&s2s[tid * 4] = *(const float4*)(s2g + kbase + tid * 4);

  // prologue: adj(0) into regs
  int4 ca[8];
#pragma unroll
  for (int j = 0; j < 8; ++j) ca[j] = *(const int4*)(abase + (size_t)j * 4 * NN);
  float la[8] = {0.f, 0.f, 0.f, 0.f, 0.f, 0.f, 0.f, 0.f};

  f32x4_t acc[4][8];
  const f32x4_t zero4 = {0.f, 0.f, 0.f, 0.f};
#pragma unroll
  for (int rt = 0; rt < 4; ++rt)
#pragma unroll
    for (int ct = 0; ct < 8; ++ct) acc[rt][ct] = zero4;

  __syncthreads();  // s2s ready (drains prologue vmem too — one-time)

  for (int it = 0; it < 16; ++it) {
    // ---- stage B(it): 32 KB via 8 gload_lds/wave ----
    {
      const char* bsrc = (const char*)whTK + (size_t)(kq * 16 + it) * 32768;
      char* bdst = (char*)Bs;
#pragma unroll
      for (int p = 0; p < 8; ++p)
        gload_lds16(bsrc + w * 8192 + p * 1024 + lane * 16, bdst + w * 8192 + p * 1024);
    }
    __builtin_amdgcn_sched_barrier(0);

    // ---- P-phase from adj regs: 8 rows x 4 ks per thread ----
    {
      float4 s2v = *(const float4*)&s2s[it * 64 + kx * 4];
#pragma unroll
      for (int j = 0; j < 8; ++j) {
        const int4 a = ca[j];
        float x0 = s1v[j] + s2v.x; x0 = fmaxf(x0, SLOPE * x0);
        float x1 = s1v[j] + s2v.y; x1 = fmaxf(x1, SLOPE * x1);
        float x2 = s1v[j] + s2v.z; x2 = fmaxf(x2, SLOPE * x2);
        float x3 = s1v[j] + s2v.w; x3 = fmaxf(x3, SLOPE * x3);
        float p0 = a.x != 0 ? __builtin_amdgcn_exp2f(x0) : 0.f;
        float p1 = a.y != 0 ? __builtin_amdgcn_exp2f(x1) : 0.f;
        float p2 = a.z != 0 ? __builtin_amdgcn_exp2f(x2) : 0.f;
        float p3 = a.w != 0 ? __builtin_amdgcn_exp2f(x3) : 0.f;
        la[j] += (p0 + p1) + (p2 + p3);
        u32x2_t wv;
        wv[0] = cvtpk(p0, p1);
        wv[1] = cvtpk(p2, p3);
        const int row = w * 32 + j * 4 + q;
        *(u32x2_t*)((char*)As + row * 128 + (((kx >> 1) ^ (row & 7)) * 16) + (kx & 1) * 8) = wv;
      }
    }

    // ---- reload adj(it+1) (stays in flight across both barriers) ----
    {
      const int itn = (it + 1 < 16) ? it + 1 : it;
#pragma unroll
      for (int j = 0; j < 8; ++j)
        ca[j] = *(const int4*)(abase + (size_t)j * 4 * NN + itn * 64);
    }
    __builtin_amdgcn_sched_barrier(0);

    // ---- barrier-1: B staged (vmcnt(8): adj loads in flight), A visible ----
    asm volatile("s_waitcnt vmcnt(8) lgkmcnt(0)" ::: "memory");
    __builtin_amdgcn_s_barrier();
    __builtin_amdgcn_sched_barrier(0);

    // ---- MFMA phase: 64 MFMA/wave ----
    {
#pragma unroll
      for (int kc = 0; kc < 2; ++kc) {
        const int ch = kc * 4 + kg;
        bf16x8_t a0, a1, a2, a3;
        {
          const int row0 = wr * 64 + r16;
          a0 = *(const bf16x8_t*)((const char*)As + (row0 + 0) * 128 + ((ch ^ ((row0 + 0) & 7)) * 16));
          a1 = *(const bf16x8_t*)((const char*)As + (row0 + 16) * 128 + ((ch ^ ((row0 + 16) & 7)) * 16));
          a2 = *(const bf16x8_t*)((const char*)As + (row0 + 32) * 128 + ((ch ^ ((row0 + 32) & 7)) * 16));
          a3 = *(const bf16x8_t*)((const char*)As + (row0 + 48) * 128 + ((ch ^ ((row0 + 48) & 7)) * 16));
        }
#pragma unroll
        for (int cp = 0; cp < 2; ++cp) {
          bf16x8_t b0, b1, b2, b3;
          {
            const int f0l = wc * 128 + cp * 64 + r16;
            b0 = *(const bf16x8_t*)((const char*)Bs + (f0l + 0) * 128 + ((ch ^ ((f0l + 0) & 7)) * 16));
            b1 = *(const bf16x8_t*)((const char*)Bs + (f0l + 16) * 128 + ((ch ^ ((f0l + 16) & 7)) * 16));
            b2 = *(const bf16x8_t*)((const char*)Bs + (f0l + 32) * 128 + ((ch ^ ((f0l + 32) & 7)) * 16));
            b3 = *(const bf16x8_t*)((const char*)Bs + (f0l + 48) * 128 + ((ch ^ ((f0l + 48) & 7)) * 16));
          }
          const int c0 = cp * 4;
          acc[0][c0 + 0] = __builtin_amdgcn_mfma_f32_16x16x32_bf16(a0, b0, acc[0][c0 + 0], 0, 0, 0);
          acc[0][c0 + 1] = __builtin_amdgcn_mfma_f32_16x16x32_bf16(a0, b1, acc[0][c0 + 1], 0, 0, 0);
          acc[0][c0 + 2] = __builtin_amdgcn_mfma_f32_16x16x32_bf16(a0, b2, acc[0][c0 + 2], 0, 0, 0);
          acc[0][c0 + 3] = __builtin_amdgcn_mfma_f32_16x16x32_bf16(a0, b3, acc[0][c0 + 3], 0, 0, 0);
          acc[1][c0 + 0] = __builtin_amdgcn_mfma_f32_16x16x32_bf16(a1, b0, acc[1][c0 + 0], 0, 0, 0);
          acc[1][c0 + 1] = __builtin_amdgcn_mfma_f32_16x16x32_bf16(a1, b1, acc[1][c0 + 1], 0, 0, 0);
          acc[1][c0 + 2] = __builtin_amdgcn_mfma_f32_16x16x32_bf16(a1, b2, acc[1][c0 + 2], 0, 0, 0);
          acc[1][c0 + 3] = __builtin_amdgcn_mfma_f32_16x16x32_bf16(a1, b3, acc[1][c0 + 3], 0, 0, 0);
          acc[2][c0 + 0] = __builtin_amdgcn_mfma_f32_16x16x32_bf16(a2, b0, acc[2][c0 + 0], 0, 0, 0);
          acc[2][c0 + 1] = __builtin_amdgcn_mfma_f32_16x16x32_bf16(a2, b1, acc[2][c0 + 1], 0, 0, 0);
          acc[2][c0 + 2] = __builtin_amdgcn_mfma_f32_16x16x32_bf16(a2, b2, acc[2][c0 + 2], 0, 0, 0);
          acc[2][c0 + 3] = __builtin_amdgcn_mfma_f32_16x16x32_bf16(a2, b3, acc[2][c0 + 3], 0, 0, 0);
          acc[3][c0 + 0] = __builtin_amdgcn_mfma_f32_16x16x32_bf16(a3, b0, acc[3][c0 + 0], 0, 0, 0);
          acc[3][c0 + 1] = __builtin_amdgcn_mfma_f32_16x16x32_bf16(a3, b1, acc[3][c0 + 1], 0, 0, 0);
          acc[3][c0 + 2] = __builtin_amdgcn_mfma_f32_16x16x32_bf16(a3, b2, acc[3][c0 + 2], 0, 0, 0);
          acc[3][c0 + 3] = __builtin_amdgcn_mfma_f32_16x16x32_bf16(a3, b3, acc[3][c0 + 3], 0, 0, 0);
        }
      }
    }

    // ---- barrier-2: LDS reads retired; adj loads stay in flight ----
    asm volatile("s_waitcnt lgkmcnt(0)" ::: "memory");
    __builtin_amdgcn_s_barrier();
    __builtin_amdgcn_sched_barrier(0);
  }

  // ---- l: reduce each row over its 16 k-chunk lanes, write directly ----
#pragma unroll
  for (int j = 0; j < 8; ++j) {
    float v = la[j];
    v += __shfl_xor(v, 1, 64);
    v += __shfl_xor(v, 2, 64);
    v += __shfl_xor(v, 4, 64);
    v += __shfl_xor(v, 8, 64);
    if ((lane & 15) == 0)
      lP[(size_t)kq * NN + rs * 128 + w * 32 + j * 4 + q] = v;
  }

  // ---- acc partials ----
  float* ap = accP + (size_t)kq * NN * FD;
#pragma unroll
  for (int rt = 0; rt < 4; ++rt) {
#pragma unroll
    for (int ct = 0; ct < 8; ++ct) {
      const int col = wc * 128 + ct * 16 + r16;
#pragma unroll
      for (int g = 0; g < 4; ++g) {
        const int row = rs * 128 + wr * 64 + rt * 16 + kg * 4 + g;
        ap[(size_t)row * FD + col] = acc[rt][ct][g];
      }
    }
  }
}

// ---------------- merge: out[i][f] = sum_kq accP / sum_kq lP -----------------
__global__ void gat_merge(const float* __restrict__ accP, const float* __restrict__ lP,
                          float* __restrict__ out) {
  const int i = blockIdx.x;
  const int f = threadIdx.x;
  float s = 0.f, l = 0.f;
#pragma unroll
  for (int q = 0; q < 8; ++q) {
    s += accP[((size_t)q * NN + i) * FD + f];
    l += lP[(size_t)q * NN + i];
  }
  out[(size_t)i * FD + f] = s / l;
}

extern "C" void kernel_launch(void* const* d_in, const int* in_sizes, int n_in,
                              void* d_out, int out_size, void* d_ws, size_t ws_size,
                              hipStream_t stream) {
  const float* h = (const float*)d_in[0];
  const int* adj = (const int*)d_in[1];
  const float* W = (const float*)d_in[2];
  const float* a = (const float*)d_in[3];
  float* out = (float*)d_out;

  char* ws = (char*)d_ws;
  unsigned short* whTK = (unsigned short*)ws;                // 4 MB
  float* s1 = (float*)(ws + 4194304);                        // 32 KB
  float* s2 = (float*)(ws + 4194304 + 32768);                // 32 KB
  float* c1 = (float*)(ws + 4194304 + 65536);                // 1 KB
  float* c2 = (float*)(ws + 4194304 + 65536 + 1024);         // 1 KB
  float* accP = (float*)(ws + 16777216);                     // 8 x 8 MB
  float* lP = (float*)(ws + 16777216 + 8ull * NN * FD * 4);  // 256 KB

  gat_cvec<<<1, 256, 0, stream>>>(W, a, c1, c2);
  gat_prep<<<2560, 256, 0, stream>>>(h, W, c1, c2, whTK, s1, s2);
  gat_attn<<<512, 256, 0, stream>>>(adj, s1, s2, whTK, accP, lP);
  gat_merge<<<NN, FD, 0, stream>>>(accP, lP, out);
}

// Round 22
// 115.854 us; speedup vs baseline: 2.1548x; 1.1657x over previous
//
#include <hip/hip_runtime.h>
#include <hip/hip_bf16.h>
#include <stdint.h>

#define NN 8192
#define FD 256
#define SLOPE 0.2f
#define LOG2E 1.44269504088896f

typedef float f32x4_t __attribute__((ext_vector_type(4)));
typedef __bf16 bf16x8_t __attribute__((ext_vector_type(8)));
typedef unsigned int u32x2_t __attribute__((ext_vector_type(2)));

__device__ __forceinline__ unsigned short f2bf(float x) {
  unsigned int u = __builtin_bit_cast(unsigned int, x);
  u += 0x7FFFu + ((u >> 16) & 1u);  // RNE
  return (unsigned short)(u >> 16);
}

__device__ __forceinline__ float bf2f(unsigned short x) {
  unsigned int u = ((unsigned int)x) << 16;
  return __builtin_bit_cast(float, u);
}

__device__ __forceinline__ unsigned int cvtpk(float lo, float hi) {
  unsigned int r;
  asm("v_cvt_pk_bf16_f32 %0, %1, %2" : "=v"(r) : "v"(lo), "v"(hi));
  return r;
}

__device__ __forceinline__ void gload_lds16(const void* g, void* l) {
  __builtin_amdgcn_global_load_lds(
      (const __attribute__((address_space(1))) uint32_t*)g,
      (__attribute__((address_space(3))) uint32_t*)l, 16, 0, 0);
}

// ---------------- kernel 0: c1/c2[k] = sum_f W[f][k]*a{1,2}[f] ----------------
__global__ void gat_cvec(const float* __restrict__ W, const float* __restrict__ a,
                         float* __restrict__ c1, float* __restrict__ c2) {
  const int k = threadIdx.x;
  float acc1 = 0.f, acc2 = 0.f;
#pragma unroll 8
  for (int f = 0; f < FD; ++f) {
    float w = W[f * FD + k];
    acc1 = fmaf(w, a[f], acc1);
    acc2 = fmaf(w, a[FD + f], acc2);
  }
  c1[k] = acc1;
  c2[k] = acc2;
}

// ---- fused prep: blocks [0,512) wht | [512,2560) svec ----------------------
// whTK[ktile(64k)][f(256)][k%64] with the G4 XOR swizzle PRE-APPLIED:
// idx = ktile*16384 + f*64 + ((k>>3)^(f&7))*8 + (k&7).   (rule #21)
__launch_bounds__(256)
__global__ void gat_prep(const float* __restrict__ h, const float* __restrict__ W,
                         const float* __restrict__ c1, const float* __restrict__ c2,
                         unsigned short* __restrict__ whTK,
                         float* __restrict__ s1, float* __restrict__ s2) {
  __shared__ __align__(16) float hT[64][64];
  __shared__ __align__(16) float wT[64][64];
  const int b = blockIdx.x;
  const int t = threadIdx.x;

  if (b < 512) {
    const int i0 = (b & 127) * 64;  // k-range (rows of Wh)
    const int f0 = (b >> 7) * 64;
    const int r = t & 63;
    const int kq = t >> 6;
    const int ty = t >> 4;
    const int tx = t & 15;
    float acc[4][4] = {};
    for (int k0 = 0; k0 < FD; k0 += 64) {
#pragma unroll
      for (int kk = 0; kk < 16; kk += 4) {
        float4 v = *(const float4*)(h + (size_t)(i0 + r) * FD + k0 + kq * 16 + kk);
        hT[kq * 16 + kk + 0][r] = v.x;
        hT[kq * 16 + kk + 1][r] = v.y;
        hT[kq * 16 + kk + 2][r] = v.z;
        hT[kq * 16 + kk + 3][r] = v.w;
        float4 u = *(const float4*)(W + (size_t)(f0 + r) * FD + k0 + kq * 16 + kk);
        wT[kq * 16 + kk + 0][r] = u.x;
        wT[kq * 16 + kk + 1][r] = u.y;
        wT[kq * 16 + kk + 2][r] = u.z;
        wT[kq * 16 + kk + 3][r] = u.w;
      }
      __syncthreads();
#pragma unroll 8
      for (int kk = 0; kk < 64; ++kk) {
        float4 av = *(const float4*)&hT[kk][ty * 4];
        float4 bv = *(const float4*)&wT[kk][tx * 4];
        acc[0][0] = fmaf(av.x, bv.x, acc[0][0]);
        acc[0][1] = fmaf(av.x, bv.y, acc[0][1]);
        acc[0][2] = fmaf(av.x, bv.z, acc[0][2]);
        acc[0][3] = fmaf(av.x, bv.w, acc[0][3]);
        acc[1][0] = fmaf(av.y, bv.x, acc[1][0]);
        acc[1][1] = fmaf(av.y, bv.y, acc[1][1]);
        acc[1][2] = fmaf(av.y, bv.z, acc[1][2]);
        acc[1][3] = fmaf(av.y, bv.w, acc[1][3]);
        acc[2][0] = fmaf(av.z, bv.x, acc[2][0]);
        acc[2][1] = fmaf(av.z, bv.y, acc[2][1]);
        acc[2][2] = fmaf(av.z, bv.z, acc[2][2]);
        acc[2][3] = fmaf(av.z, bv.w, acc[2][3]);
        acc[3][0] = fmaf(av.w, bv.x, acc[3][0]);
        acc[3][1] = fmaf(av.w, bv.y, acc[3][1]);
        acc[3][2] = fmaf(av.w, bv.z, acc[3][2]);
        acc[3][3] = fmaf(av.w, bv.w, acc[3][3]);
      }
      __syncthreads();
    }
    const int iv = i0 + ty * 4;
    const int ktile = iv >> 6;
    const int kl = iv & 63;
#pragma unroll
    for (int j = 0; j < 4; ++j) {
      const int f = f0 + tx * 4 + j;
      ushort4 o;
      o.x = f2bf(acc[0][j]);
      o.y = f2bf(acc[1][j]);
      o.z = f2bf(acc[2][j]);
      o.w = f2bf(acc[3][j]);
      const size_t idx = (size_t)ktile * 16384 + (size_t)f * 64 +
                         (size_t)(((kl >> 3) ^ (f & 7)) * 8 + (kl & 7));
      *(ushort4*)(whTK + idx) = o;
    }
  } else {
    const int i = (b - 512) * 4 + (t >> 6);
    const int lane = t & 63;
    float4 hv = *(const float4*)(h + (size_t)i * FD + lane * 4);
    float4 u = *(const float4*)(c1 + lane * 4);
    float4 v = *(const float4*)(c2 + lane * 4);
    float d1 = hv.x * u.x + hv.y * u.y + hv.z * u.z + hv.w * u.w;
    float d2 = hv.x * v.x + hv.y * v.y + hv.z * v.z + hv.w * v.w;
#pragma unroll
    for (int m = 1; m < 64; m <<= 1) {
      d1 += __shfl_xor(d1, m, 64);
      d2 += __shfl_xor(d2, m, 64);
    }
    if (lane == 0) {
      s1[i] = d1 * LOG2E;
      s2[i] = d2 * LOG2E;
    }
  }
}

// ---- attention: raw-adj fused. 128 rows x 256 f per block, m97-style -------
// grid 512 = 64 rs x 8 kq; block (rs,kq) reads adj[rs*128..)[kq*1024..) --
// each adj element read EXACTLY ONCE device-wide. Per iter: [stage B 32KB
// gload_lds] [P-VALU from adj regs -> swizzled As] [reload adj(it+1) -> regs]
// [vmcnt(8)+lgkm(0) raw barrier: B drained, adj left in flight (T4)] [64 MFMA]
// [lgkm(0) raw barrier]. Partials stored BF16 (error contribution ~3e-5; see
// r22 analysis) halving epilogue + merge traffic.
__launch_bounds__(256, 2)
__global__ void gat_attn(const int* __restrict__ adj, const float* __restrict__ s1g,
                         const float* __restrict__ s2g,
                         const unsigned short* __restrict__ whTK,
                         unsigned short* __restrict__ accP, float* __restrict__ lP) {
  __shared__ __align__(16) unsigned short Bs[64 * 256];  // [f][k] swz, 32 KB
  __shared__ __align__(16) unsigned short As[128 * 64];  // [row][k] swz, 16 KB
  __shared__ __align__(16) float s2s[1024];              // 4 KB

  const int tid = threadIdx.x;
  const int lane = tid & 63;
  const int w = tid >> 6;
  const int kq = blockIdx.x & 7;
  const int rs = blockIdx.x >> 3;
  const int kbase = kq * 1024;

  // P-phase roles
  const int q = lane >> 4;   // row subgroup 0..3
  const int kx = lane & 15;  // k-chunk (4 ints)
  const int* abase = adj + (size_t)(rs * 128 + w * 32 + q) * NN + kbase + kx * 4;
  float s1v[8];
#pragma unroll
  for (int j = 0; j < 8; ++j) s1v[j] = s1g[rs * 128 + w * 32 + j * 4 + q];

  // MFMA-phase roles
  const int wr = w & 1;
  const int wc = w >> 1;
  const int r16 = lane & 15;
  const int kg = lane >> 4;

  // stage s2 tile (block k-range)
  *(float4*)&s2s[tid * 4] = *(const float4*)(s2g + kbase + tid * 4);

  // prologue: adj(0) into regs
  int4 ca[8];
#pragma unroll
  for (int j = 0; j < 8; ++j) ca[j] = *(const int4*)(abase + (size_t)j * 4 * NN);
  float la[8] = {0.f, 0.f, 0.f, 0.f, 0.f, 0.f, 0.f, 0.f};

  f32x4_t acc[4][8];
  const f32x4_t zero4 = {0.f, 0.f, 0.f, 0.f};
#pragma unroll
  for (int rt = 0; rt < 4; ++rt)
#pragma unroll
    for (int ct = 0; ct < 8; ++ct) acc[rt][ct] = zero4;

  __syncthreads();  // s2s ready (drains prologue vmem too — one-time)

  for (int it = 0; it < 16; ++it) {
    // ---- stage B(it): 32 KB via 8 gload_lds/wave ----
    {
      const char* bsrc = (const char*)whTK + (size_t)(kq * 16 + it) * 32768;
      char* bdst = (char*)Bs;
#pragma unroll
      for (int p = 0; p < 8; ++p)
        gload_lds16(bsrc + w * 8192 + p * 1024 + lane * 16, bdst + w * 8192 + p * 1024);
    }
    __builtin_amdgcn_sched_barrier(0);

    // ---- P-phase from adj regs: 8 rows x 4 ks per thread ----
    {
      float4 s2v = *(const float4*)&s2s[it * 64 + kx * 4];
#pragma unroll
      for (int j = 0; j < 8; ++j) {
        const int4 a = ca[j];
        float x0 = s1v[j] + s2v.x; x0 = fmaxf(x0, SLOPE * x0);
        float x1 = s1v[j] + s2v.y; x1 = fmaxf(x1, SLOPE * x1);
        float x2 = s1v[j] + s2v.z; x2 = fmaxf(x2, SLOPE * x2);
        float x3 = s1v[j] + s2v.w; x3 = fmaxf(x3, SLOPE * x3);
        float p0 = a.x != 0 ? __builtin_amdgcn_exp2f(x0) : 0.f;
        float p1 = a.y != 0 ? __builtin_amdgcn_exp2f(x1) : 0.f;
        float p2 = a.z != 0 ? __builtin_amdgcn_exp2f(x2) : 0.f;
        float p3 = a.w != 0 ? __builtin_amdgcn_exp2f(x3) : 0.f;
        la[j] += (p0 + p1) + (p2 + p3);
        u32x2_t wv;
        wv[0] = cvtpk(p0, p1);
        wv[1] = cvtpk(p2, p3);
        const int row = w * 32 + j * 4 + q;
        *(u32x2_t*)((char*)As + row * 128 + (((kx >> 1) ^ (row & 7)) * 16) + (kx & 1) * 8) = wv;
      }
    }

    // ---- reload adj(it+1) (stays in flight across both barriers) ----
    {
      const int itn = (it + 1 < 16) ? it + 1 : it;
#pragma unroll
      for (int j = 0; j < 8; ++j)
        ca[j] = *(const int4*)(abase + (size_t)j * 4 * NN + itn * 64);
    }
    __builtin_amdgcn_sched_barrier(0);

    // ---- barrier-1: B staged (vmcnt(8): adj loads in flight), A visible ----
    asm volatile("s_waitcnt vmcnt(8) lgkmcnt(0)" ::: "memory");
    __builtin_amdgcn_s_barrier();
    __builtin_amdgcn_sched_barrier(0);

    // ---- MFMA phase: 64 MFMA/wave ----
    {
#pragma unroll
      for (int kc = 0; kc < 2; ++kc) {
        const int ch = kc * 4 + kg;
        bf16x8_t a0, a1, a2, a3;
        {
          const int row0 = wr * 64 + r16;
          a0 = *(const bf16x8_t*)((const char*)As + (row0 + 0) * 128 + ((ch ^ ((row0 + 0) & 7)) * 16));
          a1 = *(const bf16x8_t*)((const char*)As + (row0 + 16) * 128 + ((ch ^ ((row0 + 16) & 7)) * 16));
          a2 = *(const bf16x8_t*)((const char*)As + (row0 + 32) * 128 + ((ch ^ ((row0 + 32) & 7)) * 16));
          a3 = *(const bf16x8_t*)((const char*)As + (row0 + 48) * 128 + ((ch ^ ((row0 + 48) & 7)) * 16));
        }
#pragma unroll
        for (int cp = 0; cp < 2; ++cp) {
          bf16x8_t b0, b1, b2, b3;
          {
            const int f0l = wc * 128 + cp * 64 + r16;
            b0 = *(const bf16x8_t*)((const char*)Bs + (f0l + 0) * 128 + ((ch ^ ((f0l + 0) & 7)) * 16));
            b1 = *(const bf16x8_t*)((const char*)Bs + (f0l + 16) * 128 + ((ch ^ ((f0l + 16) & 7)) * 16));
            b2 = *(const bf16x8_t*)((const char*)Bs + (f0l + 32) * 128 + ((ch ^ ((f0l + 32) & 7)) * 16));
            b3 = *(const bf16x8_t*)((const char*)Bs + (f0l + 48) * 128 + ((ch ^ ((f0l + 48) & 7)) * 16));
          }
          const int c0 = cp * 4;
          acc[0][c0 + 0] = __builtin_amdgcn_mfma_f32_16x16x32_bf16(a0, b0, acc[0][c0 + 0], 0, 0, 0);
          acc[0][c0 + 1] = __builtin_amdgcn_mfma_f32_16x16x32_bf16(a0, b1, acc[0][c0 + 1], 0, 0, 0);
          acc[0][c0 + 2] = __builtin_amdgcn_mfma_f32_16x16x32_bf16(a0, b2, acc[0][c0 + 2], 0, 0, 0);
          acc[0][c0 + 3] = __builtin_amdgcn_mfma_f32_16x16x32_bf16(a0, b3, acc[0][c0 + 3], 0, 0, 0);
          acc[1][c0 + 0] = __builtin_amdgcn_mfma_f32_16x16x32_bf16(a1, b0, acc[1][c0 + 0], 0, 0, 0);
          acc[1][c0 + 1] = __builtin_amdgcn_mfma_f32_16x16x32_bf16(a1, b1, acc[1][c0 + 1], 0, 0, 0);
          acc[1][c0 + 2] = __builtin_amdgcn_mfma_f32_16x16x32_bf16(a1, b2, acc[1][c0 + 2], 0, 0, 0);
          acc[1][c0 + 3] = __builtin_amdgcn_mfma_f32_16x16x32_bf16(a1, b3, acc[1][c0 + 3], 0, 0, 0);
          acc[2][c0 + 0] = __builtin_amdgcn_mfma_f32_16x16x32_bf16(a2, b0, acc[2][c0 + 0], 0, 0, 0);
          acc[2][c0 + 1] = __builtin_amdgcn_mfma_f32_16x16x32_bf16(a2, b1, acc[2][c0 + 1], 0, 0, 0);
          acc[2][c0 + 2] = __builtin_amdgcn_mfma_f32_16x16x32_bf16(a2, b2, acc[2][c0 + 2], 0, 0, 0);
          acc[2][c0 + 3] = __builtin_amdgcn_mfma_f32_16x16x32_bf16(a2, b3, acc[2][c0 + 3], 0, 0, 0);
          acc[3][c0 + 0] = __builtin_amdgcn_mfma_f32_16x16x32_bf16(a3, b0, acc[3][c0 + 0], 0, 0, 0);
          acc[3][c0 + 1] = __builtin_amdgcn_mfma_f32_16x16x32_bf16(a3, b1, acc[3][c0 + 1], 0, 0, 0);
          acc[3][c0 + 2] = __builtin_amdgcn_mfma_f32_16x16x32_bf16(a3, b2, acc[3][c0 + 2], 0, 0, 0);
          acc[3][c0 + 3] = __builtin_amdgcn_mfma_f32_16x16x32_bf16(a3, b3, acc[3][c0 + 3], 0, 0, 0);
        }
      }
    }

    // ---- barrier-2: LDS reads retired; adj loads stay in flight ----
    asm volatile("s_waitcnt lgkmcnt(0)" ::: "memory");
    __builtin_amdgcn_s_barrier();
    __builtin_amdgcn_sched_barrier(0);
  }

  // ---- l: reduce each row over its 16 k-chunk lanes, write directly ----
#pragma unroll
  for (int j = 0; j < 8; ++j) {
    float v = la[j];
    v += __shfl_xor(v, 1, 64);
    v += __shfl_xor(v, 2, 64);
    v += __shfl_xor(v, 4, 64);
    v += __shfl_xor(v, 8, 64);
    if ((lane & 15) == 0)
      lP[(size_t)kq * NN + rs * 128 + w * 32 + j * 4 + q] = v;
  }

  // ---- acc partials: bf16 (halved traffic; +~3e-5 error, see analysis) ----
  unsigned short* ap = accP + (size_t)kq * NN * FD;
#pragma unroll
  for (int rt = 0; rt < 4; ++rt) {
#pragma unroll
    for (int ct = 0; ct < 8; ++ct) {
      const int col = wc * 128 + ct * 16 + r16;
#pragma unroll
      for (int g = 0; g < 4; ++g) {
        const int row = rs * 128 + wr * 64 + rt * 16 + kg * 4 + g;
        ap[(size_t)row * FD + col] = f2bf(acc[rt][ct][g]);
      }
    }
  }
}

// ---------------- merge: out[i][f] = sum_kq bf16(accP) / sum_kq lP -----------
__global__ void gat_merge(const unsigned short* __restrict__ accP,
                          const float* __restrict__ lP, float* __restrict__ out) {
  const int i = blockIdx.x;
  const int f = threadIdx.x;
  float s = 0.f, l = 0.f;
#pragma unroll
  for (int q = 0; q < 8; ++q) {
    s += bf2f(accP[((size_t)q * NN + i) * FD + f]);
    l += lP[(size_t)q * NN + i];
  }
  out[(size_t)i * FD + f] = s / l;
}

extern "C" void kernel_launch(void* const* d_in, const int* in_sizes, int n_in,
                              void* d_out, int out_size, void* d_ws, size_t ws_size,
                              hipStream_t stream) {
  const float* h = (const float*)d_in[0];
  const int* adj = (const int*)d_in[1];
  const float* W = (const float*)d_in[2];
  const float* a = (const float*)d_in[3];
  float* out = (float*)d_out;

  char* ws = (char*)d_ws;
  unsigned short* whTK = (unsigned short*)ws;                   // 4 MB
  float* s1 = (float*)(ws + 4194304);                           // 32 KB
  float* s2 = (float*)(ws + 4194304 + 32768);                   // 32 KB
  float* c1 = (float*)(ws + 4194304 + 65536);                   // 1 KB
  float* c2 = (float*)(ws + 4194304 + 65536 + 1024);            // 1 KB
  unsigned short* accP = (unsigned short*)(ws + 16777216);      // 8 x 4 MB bf16
  float* lP = (float*)(ws + 16777216 + 8ull * NN * FD * 2);     // 256 KB

  gat_cvec<<<1, 256, 0, stream>>>(W, a, c1, c2);
  gat_prep<<<2560, 256, 0, stream>>>(h, W, c1, c2, whTK, s1, s2);
  gat_attn<<<512, 256, 0, stream>>>(adj, s1, s2, whTK, accP, lP);
  gat_merge<<<NN, FD, 0, stream>>>(accP, lP, out);
}

// Round 23
// 110.865 us; speedup vs baseline: 2.2517x; 1.0450x over previous
//
#include <hip/hip_runtime.h>
#include <hip/hip_bf16.h>
#include <stdint.h>

#define NN 8192
#define FD 256
#define SLOPE 0.2f
#define LOG2E 1.44269504088896f

typedef float f32x4_t __attribute__((ext_vector_type(4)));
typedef __bf16 bf16x8_t __attribute__((ext_vector_type(8)));
typedef unsigned int u32x2_t __attribute__((ext_vector_type(2)));

__device__ __forceinline__ unsigned short f2bf(float x) {
  unsigned int u = __builtin_bit_cast(unsigned int, x);
  u += 0x7FFFu + ((u >> 16) & 1u);  // RNE
  return (unsigned short)(u >> 16);
}

__device__ __forceinline__ float bf2f(unsigned short x) {
  unsigned int u = ((unsigned int)x) << 16;
  return __builtin_bit_cast(float, u);
}

__device__ __forceinline__ unsigned int cvtpk(float lo, float hi) {
  unsigned int r;
  asm("v_cvt_pk_bf16_f32 %0, %1, %2" : "=v"(r) : "v"(lo), "v"(hi));
  return r;
}

__device__ __forceinline__ void gload_lds16(const void* g, void* l) {
  __builtin_amdgcn_global_load_lds(
      (const __attribute__((address_space(1))) uint32_t*)g,
      (__attribute__((address_space(3))) uint32_t*)l, 16, 0, 0);
}

// ---------------- kernel 0: c1/c2[k] = sum_f W[f][k]*a{1,2}[f] ----------------
__global__ void gat_cvec(const float* __restrict__ W, const float* __restrict__ a,
                         float* __restrict__ c1, float* __restrict__ c2) {
  const int k = threadIdx.x;
  float acc1 = 0.f, acc2 = 0.f;
#pragma unroll 8
  for (int f = 0; f < FD; ++f) {
    float w = W[f * FD + k];
    acc1 = fmaf(w, a[f], acc1);
    acc2 = fmaf(w, a[FD + f], acc2);
  }
  c1[k] = acc1;
  c2[k] = acc2;
}

// ---- fused prep: blocks [0,512) wht-MFMA | [512,2560) svec ------------------
// wht: Wh = h @ W^T via hi/lo bf16 split (3 MFMA products, fp32 accum; dropped
// lo*lo term ~2^-18 -> accuracy limited by the bf16 STORE, same as before).
// whTK[ktile(64k)][f(256)][k%64] with the G4 XOR swizzle PRE-APPLIED (rule #21).
__launch_bounds__(256)
__global__ void gat_prep(const float* __restrict__ h, const float* __restrict__ W,
                         const float* __restrict__ c1, const float* __restrict__ c2,
                         unsigned short* __restrict__ whTK,
                         float* __restrict__ s1, float* __restrict__ s2) {
  __shared__ __align__(16) unsigned short Ah[64 * 64];  // h hi, [i][k] swz, 8 KB
  __shared__ __align__(16) unsigned short Al[64 * 64];  // h lo
  __shared__ __align__(16) unsigned short Bh[64 * 64];  // W hi, [f][k] swz
  __shared__ __align__(16) unsigned short Bl[64 * 64];  // W lo
  const int b = blockIdx.x;
  const int t = threadIdx.x;

  if (b < 512) {
    const int i0 = (b & 127) * 64;  // Wh row range (k-dim of attn)
    const int f0 = (b >> 7) * 64;
    const int lane = t & 63;
    const int wv = t >> 6;
    const int r16 = lane & 15;
    const int kg = lane >> 4;

    f32x4_t acc[4];
    const f32x4_t zero4 = {0.f, 0.f, 0.f, 0.f};
#pragma unroll
    for (int ct = 0; ct < 4; ++ct) acc[ct] = zero4;

    for (int k0 = 0; k0 < FD; k0 += 64) {
      if (k0) __syncthreads();  // WAR: previous chunk's MFMA reads retired
      // ---- stage hi/lo tiles: thread = row r, 16-k quarter kq4 ----
      const int r = t & 63;
      const int kq4 = t >> 6;
#pragma unroll
      for (int kk = 0; kk < 16; kk += 4) {
        const int kb = kq4 * 16 + kk;  // ≡ 0 mod 4
        const int sw = ((kb >> 3) ^ (r & 7)) * 8 + (kb & 7);
        float4 v = *(const float4*)(h + (size_t)(i0 + r) * FD + k0 + kb);
        ushort4 hi, lo;
        hi.x = f2bf(v.x); lo.x = f2bf(v.x - bf2f(hi.x));
        hi.y = f2bf(v.y); lo.y = f2bf(v.y - bf2f(hi.y));
        hi.z = f2bf(v.z); lo.z = f2bf(v.z - bf2f(hi.z));
        hi.w = f2bf(v.w); lo.w = f2bf(v.w - bf2f(hi.w));
        *(ushort4*)&Ah[r * 64 + sw] = hi;
        *(ushort4*)&Al[r * 64 + sw] = lo;
        float4 u = *(const float4*)(W + (size_t)(f0 + r) * FD + k0 + kb);
        ushort4 whi, wlo;
        whi.x = f2bf(u.x); wlo.x = f2bf(u.x - bf2f(whi.x));
        whi.y = f2bf(u.y); wlo.y = f2bf(u.y - bf2f(whi.y));
        whi.z = f2bf(u.z); wlo.z = f2bf(u.z - bf2f(whi.z));
        whi.w = f2bf(u.w); wlo.w = f2bf(u.w - bf2f(whi.w));
        *(ushort4*)&Bh[r * 64 + sw] = whi;
        *(ushort4*)&Bl[r * 64 + sw] = wlo;
      }
      __syncthreads();
      // ---- MFMA: wave wv owns rows [wv*16, +16) x all 64 f ----
#pragma unroll
      for (int kc = 0; kc < 2; ++kc) {
        const int ch = kc * 4 + kg;
        const int arow = wv * 16 + r16;
        const int aoff = arow * 64 + (ch ^ (arow & 7)) * 8;
        bf16x8_t ah = *(const bf16x8_t*)&Ah[aoff];
        bf16x8_t al = *(const bf16x8_t*)&Al[aoff];
#pragma unroll
        for (int ct = 0; ct < 4; ++ct) {
          const int brow = ct * 16 + r16;
          const int boff = brow * 64 + (ch ^ (brow & 7)) * 8;
          bf16x8_t bh = *(const bf16x8_t*)&Bh[boff];
          bf16x8_t bl = *(const bf16x8_t*)&Bl[boff];
          acc[ct] = __builtin_amdgcn_mfma_f32_16x16x32_bf16(ah, bh, acc[ct], 0, 0, 0);
          acc[ct] = __builtin_amdgcn_mfma_f32_16x16x32_bf16(ah, bl, acc[ct], 0, 0, 0);
          acc[ct] = __builtin_amdgcn_mfma_f32_16x16x32_bf16(al, bh, acc[ct], 0, 0, 0);
        }
      }
    }
    // ---- epilogue: i = i0 + wv*16 + kg*4 + g, f = f0 + ct*16 + r16 ----
    const int kl0 = wv * 16 + kg * 4;  // i within 64-tile (≡0 mod 4)
    const int ktile = i0 >> 6;
#pragma unroll
    for (int ct = 0; ct < 4; ++ct) {
      const int f = f0 + ct * 16 + r16;
      ushort4 o;
      o.x = f2bf(acc[ct][0]);
      o.y = f2bf(acc[ct][1]);
      o.z = f2bf(acc[ct][2]);
      o.w = f2bf(acc[ct][3]);
      const size_t idx = (size_t)ktile * 16384 + (size_t)f * 64 +
                         (size_t)(((kl0 >> 3) ^ (f & 7)) * 8 + (kl0 & 7));
      *(ushort4*)(whTK + idx) = o;
    }
  } else {
    const int i = (b - 512) * 4 + (t >> 6);
    const int lane = t & 63;
    float4 hv = *(const float4*)(h + (size_t)i * FD + lane * 4);
    float4 u = *(const float4*)(c1 + lane * 4);
    float4 v = *(const float4*)(c2 + lane * 4);
    float d1 = hv.x * u.x + hv.y * u.y + hv.z * u.z + hv.w * u.w;
    float d2 = hv.x * v.x + hv.y * v.y + hv.z * v.z + hv.w * v.w;
#pragma unroll
    for (int m = 1; m < 64; m <<= 1) {
      d1 += __shfl_xor(d1, m, 64);
      d2 += __shfl_xor(d2, m, 64);
    }
    if (lane == 0) {
      s1[i] = d1 * LOG2E;
      s2[i] = d2 * LOG2E;
    }
  }
}

// ---- attention: raw-adj fused. 128 rows x 256 f per block, m97-style -------
// grid 512 = 64 rs x 8 kq; block (rs,kq) reads adj[rs*128..)[kq*1024..) --
// each adj element read EXACTLY ONCE device-wide. Per iter: [stage B 32KB
// gload_lds] [P-VALU from adj regs -> swizzled As] [reload adj(it+1) -> regs]
// [vmcnt(8)+lgkm(0) raw barrier: B drained, adj left in flight (T4)] [64 MFMA]
// [lgkm(0) raw barrier]. Partials stored BF16 (error ~3e-5).
__launch_bounds__(256, 2)
__global__ void gat_attn(const int* __restrict__ adj, const float* __restrict__ s1g,
                         const float* __restrict__ s2g,
                         const unsigned short* __restrict__ whTK,
                         unsigned short* __restrict__ accP, float* __restrict__ lP) {
  __shared__ __align__(16) unsigned short Bs[64 * 256];  // [f][k] swz, 32 KB
  __shared__ __align__(16) unsigned short As[128 * 64];  // [row][k] swz, 16 KB
  __shared__ __align__(16) float s2s[1024];              // 4 KB

  const int tid = threadIdx.x;
  const int lane = tid & 63;
  const int w = tid >> 6;
  const int kq = blockIdx.x & 7;
  const int rs = blockIdx.x >> 3;
  const int kbase = kq * 1024;

  // P-phase roles
  const int q = lane >> 4;   // row subgroup 0..3
  const int kx = lane & 15;  // k-chunk (4 ints)
  const int* abase = adj + (size_t)(rs * 128 + w * 32 + q) * NN + kbase + kx * 4;
  float s1v[8];
#pragma unroll
  for (int j = 0; j < 8; ++j) s1v[j] = s1g[rs * 128 + w * 32 + j * 4 + q];

  // MFMA-phase roles
  const int wr = w & 1;
  const int wc = w >> 1;
  const int r16 = lane & 15;
  const int kg = lane >> 4;

  // stage s2 tile (block k-range)
  *(float4*)&s2s[tid * 4] = *(const float4*)(s2g + kbase + tid * 4);

  // prologue: adj(0) into regs
  int4 ca[8];
#pragma unroll
  for (int j = 0; j < 8; ++j) ca[j] = *(const int4*)(abase + (size_t)j * 4 * NN);
  float la[8] = {0.f, 0.f, 0.f, 0.f, 0.f, 0.f, 0.f, 0.f};

  f32x4_t acc[4][8];
  const f32x4_t zero4 = {0.f, 0.f, 0.f, 0.f};
#pragma unroll
  for (int rt = 0; rt < 4; ++rt)
#pragma unroll
    for (int ct = 0; ct < 8; ++ct) acc[rt][ct] = zero4;

  __syncthreads();  // s2s ready (drains prologue vmem too — one-time)

  for (int it = 0; it < 16; ++it) {
    // ---- stage B(it): 32 KB via 8 gload_lds/wave ----
    {
      const char* bsrc = (const char*)whTK + (size_t)(kq * 16 + it) * 32768;
      char* bdst = (char*)Bs;
#pragma unroll
      for (int p = 0; p < 8; ++p)
        gload_lds16(bsrc + w * 8192 + p * 1024 + lane * 16, bdst + w * 8192 + p * 1024);
    }
    __builtin_amdgcn_sched_barrier(0);

    // ---- P-phase from adj regs: 8 rows x 4 ks per thread ----
    {
      float4 s2v = *(const float4*)&s2s[it * 64 + kx * 4];
#pragma unroll
      for (int j = 0; j < 8; ++j) {
        const int4 a = ca[j];
        float x0 = s1v[j] + s2v.x; x0 = fmaxf(x0, SLOPE * x0);
        float x1 = s1v[j] + s2v.y; x1 = fmaxf(x1, SLOPE * x1);
        float x2 = s1v[j] + s2v.z; x2 = fmaxf(x2, SLOPE * x2);
        float x3 = s1v[j] + s2v.w; x3 = fmaxf(x3, SLOPE * x3);
        float p0 = a.x != 0 ? __builtin_amdgcn_exp2f(x0) : 0.f;
        float p1 = a.y != 0 ? __builtin_amdgcn_exp2f(x1) : 0.f;
        float p2 = a.z != 0 ? __builtin_amdgcn_exp2f(x2) : 0.f;
        float p3 = a.w != 0 ? __builtin_amdgcn_exp2f(x3) : 0.f;
        la[j] += (p0 + p1) + (p2 + p3);
        u32x2_t wv;
        wv[0] = cvtpk(p0, p1);
        wv[1] = cvtpk(p2, p3);
        const int row = w * 32 + j * 4 + q;
        *(u32x2_t*)((char*)As + row * 128 + (((kx >> 1) ^ (row & 7)) * 16) + (kx & 1) * 8) = wv;
      }
    }

    // ---- reload adj(it+1) (stays in flight across both barriers) ----
    {
      const int itn = (it + 1 < 16) ? it + 1 : it;
#pragma unroll
      for (int j = 0; j < 8; ++j)
        ca[j] = *(const int4*)(abase + (size_t)j * 4 * NN + itn * 64);
    }
    __builtin_amdgcn_sched_barrier(0);

    // ---- barrier-1: B staged (vmcnt(8): adj loads in flight), A visible ----
    asm volatile("s_waitcnt vmcnt(8) lgkmcnt(0)" ::: "memory");
    __builtin_amdgcn_s_barrier();
    __builtin_amdgcn_sched_barrier(0);

    // ---- MFMA phase: 64 MFMA/wave ----
    {
#pragma unroll
      for (int kc = 0; kc < 2; ++kc) {
        const int ch = kc * 4 + kg;
        bf16x8_t a0, a1, a2, a3;
        {
          const int row0 = wr * 64 + r16;
          a0 = *(const bf16x8_t*)((const char*)As + (row0 + 0) * 128 + ((ch ^ ((row0 + 0) & 7)) * 16));
          a1 = *(const bf16x8_t*)((const char*)As + (row0 + 16) * 128 + ((ch ^ ((row0 + 16) & 7)) * 16));
          a2 = *(const bf16x8_t*)((const char*)As + (row0 + 32) * 128 + ((ch ^ ((row0 + 32) & 7)) * 16));
          a3 = *(const bf16x8_t*)((const char*)As + (row0 + 48) * 128 + ((ch ^ ((row0 + 48) & 7)) * 16));
        }
#pragma unroll
        for (int cp = 0; cp < 2; ++cp) {
          bf16x8_t b0, b1, b2, b3;
          {
            const int f0l = wc * 128 + cp * 64 + r16;
            b0 = *(const bf16x8_t*)((const char*)Bs + (f0l + 0) * 128 + ((ch ^ ((f0l + 0) & 7)) * 16));
            b1 = *(const bf16x8_t*)((const char*)Bs + (f0l + 16) * 128 + ((ch ^ ((f0l + 16) & 7)) * 16));
            b2 = *(const bf16x8_t*)((const char*)Bs + (f0l + 32) * 128 + ((ch ^ ((f0l + 32) & 7)) * 16));
            b3 = *(const bf16x8_t*)((const char*)Bs + (f0l + 48) * 128 + ((ch ^ ((f0l + 48) & 7)) * 16));
          }
          const int c0 = cp * 4;
          acc[0][c0 + 0] = __builtin_amdgcn_mfma_f32_16x16x32_bf16(a0, b0, acc[0][c0 + 0], 0, 0, 0);
          acc[0][c0 + 1] = __builtin_amdgcn_mfma_f32_16x16x32_bf16(a0, b1, acc[0][c0 + 1], 0, 0, 0);
          acc[0][c0 + 2] = __builtin_amdgcn_mfma_f32_16x16x32_bf16(a0, b2, acc[0][c0 + 2], 0, 0, 0);
          acc[0][c0 + 3] = __builtin_amdgcn_mfma_f32_16x16x32_bf16(a0, b3, acc[0][c0 + 3], 0, 0, 0);
          acc[1][c0 + 0] = __builtin_amdgcn_mfma_f32_16x16x32_bf16(a1, b0, acc[1][c0 + 0], 0, 0, 0);
          acc[1][c0 + 1] = __builtin_amdgcn_mfma_f32_16x16x32_bf16(a1, b1, acc[1][c0 + 1], 0, 0, 0);
          acc[1][c0 + 2] = __builtin_amdgcn_mfma_f32_16x16x32_bf16(a1, b2, acc[1][c0 + 2], 0, 0, 0);
          acc[1][c0 + 3] = __builtin_amdgcn_mfma_f32_16x16x32_bf16(a1, b3, acc[1][c0 + 3], 0, 0, 0);
          acc[2][c0 + 0] = __builtin_amdgcn_mfma_f32_16x16x32_bf16(a2, b0, acc[2][c0 + 0], 0, 0, 0);
          acc[2][c0 + 1] = __builtin_amdgcn_mfma_f32_16x16x32_bf16(a2, b1, acc[2][c0 + 1], 0, 0, 0);
          acc[2][c0 + 2] = __builtin_amdgcn_mfma_f32_16x16x32_bf16(a2, b2, acc[2][c0 + 2], 0, 0, 0);
          acc[2][c0 + 3] = __builtin_amdgcn_mfma_f32_16x16x32_bf16(a2, b3, acc[2][c0 + 3], 0, 0, 0);
          acc[3][c0 + 0] = __builtin_amdgcn_mfma_f32_16x16x32_bf16(a3, b0, acc[3][c0 + 0], 0, 0, 0);
          acc[3][c0 + 1] = __builtin_amdgcn_mfma_f32_16x16x32_bf16(a3, b1, acc[3][c0 + 1], 0, 0, 0);
          acc[3][c0 + 2] = __builtin_amdgcn_mfma_f32_16x16x32_bf16(a3, b2, acc[3][c0 + 2], 0, 0, 0);
          acc[3][c0 + 3] = __builtin_amdgcn_mfma_f32_16x16x32_bf16(a3, b3, acc[3][c0 + 3], 0, 0, 0);
        }
      }
    }

    // ---- barrier-2: LDS reads retired; adj loads stay in flight ----
    asm volatile("s_waitcnt lgkmcnt(0)" ::: "memory");
    __builtin_amdgcn_s_barrier();
    __builtin_amdgcn_sched_barrier(0);
  }

  // ---- l: reduce each row over its 16 k-chunk lanes, write directly ----
#pragma unroll
  for (int j = 0; j < 8; ++j) {
    float v = la[j];
    v += __shfl_xor(v, 1, 64);
    v += __shfl_xor(v, 2, 64);
    v += __shfl_xor(v, 4, 64);
    v += __shfl_xor(v, 8, 64);
    if ((lane & 15) == 0)
      lP[(size_t)kq * NN + rs * 128 + w * 32 + j * 4 + q] = v;
  }

  // ---- acc partials: bf16 (halved traffic) ----
  unsigned short* ap = accP + (size_t)kq * NN * FD;
#pragma unroll
  for (int rt = 0; rt < 4; ++rt) {
#pragma unroll
    for (int ct = 0; ct < 8; ++ct) {
      const int col = wc * 128 + ct * 16 + r16;
#pragma unroll
      for (int g = 0; g < 4; ++g) {
        const int row = rs * 128 + wr * 64 + rt * 16 + kg * 4 + g;
        ap[(size_t)row * FD + col] = f2bf(acc[rt][ct][g]);
      }
    }
  }
}

// ---------------- merge: out[i][f] = sum_kq bf16(accP) / sum_kq lP -----------
__global__ void gat_merge(const unsigned short* __restrict__ accP,
                          const float* __restrict__ lP, float* __restrict__ out) {
  const int i = blockIdx.x;
  const int f = threadIdx.x;
  float s = 0.f, l = 0.f;
#pragma unroll
  for (int q = 0; q < 8; ++q) {
    s += bf2f(accP[((size_t)q * NN + i) * FD + f]);
    l += lP[(size_t)q * NN + i];
  }
  out[(size_t)i * FD + f] = s / l;
}

extern "C" void kernel_launch(void* const* d_in, const int* in_sizes, int n_in,
                              void* d_out, int out_size, void* d_ws, size_t ws_size,
                              hipStream_t stream) {
  const float* h = (const float*)d_in[0];
  const int* adj = (const int*)d_in[1];
  const float* W = (const float*)d_in[2];
  const float* a = (const float*)d_in[3];
  float* out = (float*)d_out;

  char* ws = (char*)d_ws;
  unsigned short* whTK = (unsigned short*)ws;                // 4 MB
  float* s1 = (float*)(ws + 4194304);                        // 32 KB
  float* s2 = (float*)(ws + 4194304 + 32768);                // 32 KB
  float* c1 = (float*)(ws + 4194304 + 65536);                // 1 KB
  float* c2 = (float*)(ws + 4194304 + 65536 + 1024);         // 1 KB
  unsigned short* accP = (unsigned short*)(ws + 16777216);   // 8 x 4 MB bf16
  float* lP = (float*)(ws + 16777216 + 8ull * NN * FD * 2);  // 256 KB

  gat_cvec<<<1, 256, 0, stream>>>(W, a, c1, c2);
  gat_prep<<<2560, 256, 0, stream>>>(h, W, c1, c2, whTK, s1, s2);
  gat_attn<<<512, 256, 0, stream>>>(adj, s1, s2, whTK, accP, lP);
  gat_merge<<<NN, FD, 0, stream>>>(accP, lP, out);
}